// Round 5
// baseline (642.611 us; speedup 1.0000x reference)
//
#include <hip/hip_runtime.h>
#include <cstdint>
#include <cstddef>

static constexpr int DIN  = 128;
static constexpr int DH   = 256;
static constexpr int DOUT = 47;

typedef __attribute__((ext_vector_type(8))) short bf16x8;
typedef __attribute__((ext_vector_type(4))) float f32x4;
typedef __attribute__((ext_vector_type(2))) float f32x2;

__device__ __forceinline__ short f2bf(float f) {
    unsigned u = __float_as_uint(f);
    unsigned r = (u + 0x7fffu + ((u >> 16) & 1u)) >> 16;  // RNE
    return (short)r;
}

// fp8 e4m3 (HW-native) helpers
__device__ __forceinline__ void addpk(unsigned w, float* a) {
    f32x2 lo = __builtin_amdgcn_cvt_pk_f32_fp8(w, false);
    f32x2 hi = __builtin_amdgcn_cvt_pk_f32_fp8(w, true);
    a[0] += lo[0]; a[1] += lo[1]; a[2] += hi[0]; a[3] += hi[1];
}
__device__ __forceinline__ unsigned enc4(float a, float b, float c, float d) {
    unsigned w = __builtin_amdgcn_cvt_pk_fp8_f32(a, b, 0, false);
    w = __builtin_amdgcn_cvt_pk_fp8_f32(c, d, w, true);
    return w;
}
__device__ __forceinline__ unsigned char enc1(float v) {
    return (unsigned char)(__builtin_amdgcn_cvt_pk_fp8_f32(v, v, 0, false) & 0xff);
}
__device__ __forceinline__ unsigned pbf2(float a, float b, float sc) {
    return (unsigned)(unsigned short)f2bf(a * sc) |
           ((unsigned)(unsigned short)f2bf(b * sc) << 16);
}

// ---------------------------------------------------------------------------
// CSR build
__global__ void k_detect(const int* __restrict__ e, int* __restrict__ flag, int nprobe) {
    int i = blockIdx.x * blockDim.x + threadIdx.x;
    if (i < nprobe) {
        if (e[2 * i + 1] != 0) atomicOr(flag, 1);
    }
}

// Legacy fallback path (used only when bucket params don't fit)
__global__ void k_hist(const int* __restrict__ e, const int* __restrict__ flag,
                       int* __restrict__ cnt, int E) {
    int i = blockIdx.x * blockDim.x + threadIdx.x;
    if (i >= E) return;
    int is32 = *flag;
    int d = is32 ? e[E + i] : e[2 * (E + i)];
    atomicAdd(&cnt[d], 1);
}

__global__ void k_fill(const int* __restrict__ e, const int* __restrict__ flag,
                       const int* __restrict__ rowptr, int* __restrict__ cursor,
                       int* __restrict__ colbuf, int E) {
    int i = blockIdx.x * blockDim.x + threadIdx.x;
    if (i >= E) return;
    int is32 = *flag;
    int s = is32 ? e[i] : e[2 * i];
    int d = is32 ? e[E + i] : e[2 * (E + i)];
    int pos = atomicAdd(&cursor[d], 1);
    colbuf[rowptr[d] + pos] = s;
}

// --- Fast bucketed CSR build ------------------------------------------------
// Buckets of (1<<shift) nodes; nbk <= 1024, span <= 2048.

// Per-block LDS histogram of edge dst-buckets -> global bucketCnt.
__launch_bounds__(256)
__global__ void k_binhist(const int* __restrict__ e, const int* __restrict__ flag,
                          int* __restrict__ bucketCnt, int E, int shift, int nbk) {
    __shared__ int h[1024];
    int t = threadIdx.x;
    for (int i = t; i < nbk; i += 256) h[i] = 0;
    __syncthreads();
    int is32 = *flag;
    int stride = gridDim.x * 256;
    for (int i = blockIdx.x * 256 + t; i < E; i += stride) {
        int d = is32 ? e[E + i] : e[2 * (E + i)];
        atomicAdd(&h[d >> shift], 1);
    }
    __syncthreads();
    for (int i = t; i < nbk; i += 256) {
        int v = h[i];
        if (v) atomicAdd(&bucketCnt[i], v);
    }
}

// Exclusive scan of bucket counts (single block) + zero bucket cursors.
__global__ void k_bucket_scan(const int* __restrict__ bucketCnt, int* __restrict__ bucketOff,
                              int* __restrict__ bucketCur, int nbk, int E) {
    __shared__ int s[1024];
    int t = threadIdx.x;
    int v = (t < nbk) ? bucketCnt[t] : 0;
    s[t] = v;
    __syncthreads();
    for (int off = 1; off < 1024; off <<= 1) {
        int xv = (t >= off) ? s[t - off] : 0;
        __syncthreads();
        s[t] += xv;
        __syncthreads();
    }
    if (t < nbk) { bucketOff[t] = s[t] - v; bucketCur[t] = 0; }
    if (t == 0) bucketOff[nbk] = E;
}

// Scatter (src,dst) pairs grouped by bucket. Each block owns a contiguous
// chunk of edges, reserves per-bucket ranges with ONE atomic per
// (block,bucket), then places edges via LDS cursors -> dense writes.
__launch_bounds__(256)
__global__ void k_binscatter(const int* __restrict__ e, const int* __restrict__ flag,
                             const int* __restrict__ bucketOff, int* __restrict__ bucketCur,
                             uint2* __restrict__ pairbuf, int E, int shift, int nbk) {
    __shared__ int h[1024];     // phase1: local counts; phase2: global write base
    __shared__ int cur[1024];
    int t = threadIdx.x;
    for (int i = t; i < nbk; i += 256) h[i] = 0;
    __syncthreads();
    int is32 = *flag;
    int chunk = (E + gridDim.x - 1) / gridDim.x;
    int lo = blockIdx.x * chunk;
    int hi = lo + chunk < E ? lo + chunk : E;
    for (int i = lo + t; i < hi; i += 256) {
        int d = is32 ? e[E + i] : e[2 * (E + i)];
        atomicAdd(&h[d >> shift], 1);
    }
    __syncthreads();
    for (int i = t; i < nbk; i += 256) {
        int c = h[i];
        int base = c ? atomicAdd(&bucketCur[i], c) : 0;
        h[i] = bucketOff[i] + base;
        cur[i] = 0;
    }
    __syncthreads();
    for (int i = lo + t; i < hi; i += 256) {
        int sv = is32 ? e[i] : e[2 * i];
        int d  = is32 ? e[E + i] : e[2 * (E + i)];
        int b = d >> shift;
        int lp = atomicAdd(&cur[b], 1);
        pairbuf[h[b] + lp] = make_uint2((unsigned)sv, (unsigned)d);
    }
}

// Per-bucket degree histogram in LDS -> cnt (no global atomics: buckets
// partition the node range).
__launch_bounds__(256)
__global__ void k_bhist(const uint2* __restrict__ pairbuf, const int* __restrict__ bucketOff,
                        int* __restrict__ cnt, int shift, int N) {
    __shared__ int h[2048];
    int b = blockIdx.x;
    int t = threadIdx.x;
    int first = b << shift;
    int span = (1 << shift);
    if (first + span > N) span = N - first;
    for (int i = t; i < span; i += 256) h[i] = 0;
    __syncthreads();
    int lo = bucketOff[b], hi = bucketOff[b + 1];
    for (int j = lo + t; j < hi; j += 256) {
        int d = (int)pairbuf[j].y;
        atomicAdd(&h[d - first], 1);
    }
    __syncthreads();
    for (int i = t; i < span; i += 256) cnt[first + i] = h[i];
}

// Per-bucket CSR fill: LDS cursors + LDS staging, single coalesced stream-out
// of the bucket's contiguous colbuf range. Global-atomic fallback for
// oversized buckets keeps correctness on adversarial inputs.
#define FILL_CAP 12288
__launch_bounds__(256)
__global__ void k_fill2(const uint2* __restrict__ pairbuf, const int* __restrict__ bucketOff,
                        const int* __restrict__ rowptr, int* __restrict__ cursor,
                        int* __restrict__ colbuf, int shift, int N) {
    __shared__ int cur[2048];
    __shared__ int sbuf[FILL_CAP];
    int b = blockIdx.x;
    int t = threadIdx.x;
    int first = b << shift;
    int span = (1 << shift);
    if (first + span > N) span = N - first;
    int lo = bucketOff[b], hi = bucketOff[b + 1];
    int nEdge = hi - lo;
    int base = rowptr[first];
    if (nEdge <= FILL_CAP) {
        for (int i = t; i < span; i += 256) cur[i] = rowptr[first + i] - base;
        __syncthreads();
        for (int j = lo + t; j < hi; j += 256) {
            uint2 p = pairbuf[j];
            int lp = atomicAdd(&cur[(int)p.y - first], 1);
            sbuf[lp] = (int)p.x;
        }
        __syncthreads();
        for (int i = t; i < nEdge; i += 256) colbuf[base + i] = sbuf[i];
    } else {
        for (int j = lo + t; j < hi; j += 256) {
            uint2 p = pairbuf[j];
            int d = (int)p.y;
            int pos = atomicAdd(&cursor[d], 1);
            colbuf[rowptr[d] + pos] = (int)p.x;
        }
    }
}

__global__ void k_chunk_sum(const int* __restrict__ cnt, int* __restrict__ csum, int n) {
    int base = blockIdx.x * 1024;
    int t = threadIdx.x;
    int s = 0;
#pragma unroll
    for (int j = 0; j < 4; j++) {
        int i = base + t * 4 + j;
        if (i < n) s += cnt[i];
    }
    __shared__ int red[256];
    red[t] = s;
    __syncthreads();
    for (int off = 128; off > 0; off >>= 1) {
        if (t < off) red[t] += red[t + off];
        __syncthreads();
    }
    if (t == 0) csum[blockIdx.x] = red[0];
}

__global__ void k_scan_csum(int* __restrict__ csum, int n,
                            int* __restrict__ rowptr, int N, int E) {
    __shared__ int s[128];
    int t = threadIdx.x;
    int v = (t < n) ? csum[t] : 0;
    s[t] = v;
    __syncthreads();
    for (int off = 1; off < 128; off <<= 1) {
        int xv = (t >= off) ? s[t - off] : 0;
        __syncthreads();
        s[t] += xv;
        __syncthreads();
    }
    if (t < n) csum[t] = s[t] - v;  // exclusive
    if (t == 0) rowptr[N] = E;
}

__global__ void k_scan_apply(const int* __restrict__ cnt, const int* __restrict__ csum,
                             int* __restrict__ rowptr, int n) {
    int base = blockIdx.x * 1024, t = threadIdx.x;
    int i0 = base + t * 4;
    int v[4];
#pragma unroll
    for (int j = 0; j < 4; j++) {
        int i = i0 + j;
        v[j] = (i < n) ? cnt[i] : 0;
    }
    int tsum = v[0] + v[1] + v[2] + v[3];
    __shared__ int s[256];
    s[t] = tsum;
    __syncthreads();
    for (int off = 1; off < 256; off <<= 1) {
        int xv = (t >= off) ? s[t - off] : 0;
        __syncthreads();
        s[t] += xv;
        __syncthreads();
    }
    int excl = s[t] - tsum + csum[blockIdx.x];
#pragma unroll
    for (int j = 0; j < 4; j++) {
        int i = i0 + j;
        if (i < n) rowptr[i] = excl;
        excl += v[j];
    }
}

__global__ void k_invdeg(const int* __restrict__ rowptr, float* __restrict__ invd, int N) {
    int i = blockIdx.x * blockDim.x + threadIdx.x;
    if (i >= N) return;
    int d = rowptr[i + 1] - rowptr[i];
    invd[i] = 1.0f / (float)(d > 1 ? d : 1);
}

// ---------------------------------------------------------------------------
// fp32 x -> bf16 (GEMM A2) + fp8 (gather table)
__global__ void k_f2bf8(const float* __restrict__ X, short* __restrict__ Yb,
                        unsigned* __restrict__ Y8, int n4) {
    int i = blockIdx.x * 256 + threadIdx.x;
    if (i >= n4) return;
    float4 v = *(const float4*)(X + (size_t)i * 4);
    short4 o;
    o.x = f2bf(v.x); o.y = f2bf(v.y); o.z = f2bf(v.z); o.w = f2bf(v.w);
    *(short4*)(Yb + (size_t)i * 4) = o;
    Y8[i] = enc4(v.x, v.y, v.z, v.w);
}

// Pack fp32 weight [K, Ncols] into bf16 B-fragment order for mfma_16x16x32
__global__ void k_pack(const float* __restrict__ W, short* __restrict__ P,
                       int ksteps, int Nt, int Ncols) {
    int idx = blockIdx.x * 256 + threadIdx.x;
    int total = ksteps * Nt * 64;
    if (idx >= total) return;
    int lane = idx & 63;
    int t = idx >> 6;
    int nt = t % Nt;
    int ks = t / Nt;
    int n = nt * 16 + (lane & 15);
    int kb = ks * 32 + (lane >> 4) * 8;
    bf16x8 o;
#pragma unroll
    for (int j = 0; j < 8; j++)
        o[j] = (n < Ncols) ? f2bf(W[(size_t)(kb + j) * Ncols + n]) : (short)0;
    *(bf16x8*)(P + (size_t)idx * 8) = o;
}

// ---------------------------------------------------------------------------
// 256-wide fp8 CSR mean-agg: quarter-wave owns a row (16 lanes x 16B = 256B),
// 8 neighbors/iter in 2 uint4 gathers. Output bf16 (GEMM A1 input).
__launch_bounds__(256)
__global__ void k_agg256_f8(const unsigned char* __restrict__ X8, const int* __restrict__ rowptr,
                            const int* __restrict__ colv, const float* __restrict__ invd,
                            short* __restrict__ out, int N) {
    const int lane = threadIdx.x & 63;
    const int node = blockIdx.x * 4 + (threadIdx.x >> 6);
    if (node >= N) return;
    int beg = __builtin_amdgcn_readfirstlane(rowptr[node]);
    int end = __builtin_amdgcn_readfirstlane(rowptr[node + 1]);
    const int q = lane >> 4, sub = lane & 15;
    const unsigned char* Xs = X8 + sub * 16;

    float acc[16];
#pragma unroll
    for (int c = 0; c < 16; c++) acc[c] = 0.f;

    auto addv = [&](uint4 a) {
        addpk(a.x, acc); addpk(a.y, acc + 4); addpk(a.z, acc + 8); addpk(a.w, acc + 12);
    };

    int j = beg;
    for (; j + 7 < end; j += 8) {
        int i0 = colv[j], i1 = colv[j + 1], i2 = colv[j + 2], i3 = colv[j + 3];
        int i4 = colv[j + 4], i5 = colv[j + 5], i6 = colv[j + 6], i7 = colv[j + 7];
        int sA = (q == 0) ? i0 : (q == 1) ? i1 : (q == 2) ? i2 : i3;
        int sB = (q == 0) ? i4 : (q == 1) ? i5 : (q == 2) ? i6 : i7;
        uint4 a = *(const uint4*)(Xs + (size_t)sA * 256);
        uint4 b = *(const uint4*)(Xs + (size_t)sB * 256);
        addv(a); addv(b);
    }
    if (j + 3 < end) {
        int i0 = colv[j], i1 = colv[j + 1], i2 = colv[j + 2], i3 = colv[j + 3];
        int sA = (q == 0) ? i0 : (q == 1) ? i1 : (q == 2) ? i2 : i3;
        uint4 a = *(const uint4*)(Xs + (size_t)sA * 256);
        addv(a);
        j += 4;
    }
    int rem = end - j;
    if (rem > 0) {
        int i0 = colv[j];
        int i1 = rem > 1 ? colv[j + 1] : i0;
        int i2 = rem > 2 ? colv[j + 2] : i0;
        int s = (q == 1) ? i1 : (q == 2) ? i2 : i0;
        uint4 a = *(const uint4*)(Xs + (size_t)s * 256);
        if (q < rem) addv(a);
    }

#pragma unroll
    for (int c = 0; c < 16; c++) {
        acc[c] += __shfl_xor(acc[c], 16);
        acc[c] += __shfl_xor(acc[c], 32);
    }

    if (q == 0) {
        float sc = invd[node];
        uint4 o0, o1;
        o0.x = pbf2(acc[0], acc[1], sc);   o0.y = pbf2(acc[2], acc[3], sc);
        o0.z = pbf2(acc[4], acc[5], sc);   o0.w = pbf2(acc[6], acc[7], sc);
        o1.x = pbf2(acc[8], acc[9], sc);   o1.y = pbf2(acc[10], acc[11], sc);
        o1.z = pbf2(acc[12], acc[13], sc); o1.w = pbf2(acc[14], acc[15], sc);
        short* op = out + (size_t)node * 256 + sub * 16;
        *(uint4*)op = o0;
        *(uint4*)(op + 8) = o1;
    }
}

// 128-wide fp8 CSR mean-agg: eighth-wave owns a row (8 lanes x 16B = 128B),
// 16 neighbors/iter in 2 uint4 gathers.
__launch_bounds__(256)
__global__ void k_agg128_f8(const unsigned char* __restrict__ X8, const int* __restrict__ rowptr,
                            const int* __restrict__ colv, const float* __restrict__ invd,
                            short* __restrict__ out, int N) {
    const int lane = threadIdx.x & 63;
    const int node = blockIdx.x * 4 + (threadIdx.x >> 6);
    if (node >= N) return;
    int beg = __builtin_amdgcn_readfirstlane(rowptr[node]);
    int end = __builtin_amdgcn_readfirstlane(rowptr[node + 1]);
    const int grp = lane >> 3, sub = lane & 7;
    const unsigned char* Xs = X8 + sub * 16;

    float acc[16];
#pragma unroll
    for (int c = 0; c < 16; c++) acc[c] = 0.f;

    auto addv = [&](uint4 a) {
        addpk(a.x, acc); addpk(a.y, acc + 4); addpk(a.z, acc + 8); addpk(a.w, acc + 12);
    };

    int j = beg;
    for (; j + 15 < end; j += 16) {
        int sA = colv[j + grp];
        int sB = colv[j + 8 + grp];
        uint4 a = *(const uint4*)(Xs + (size_t)sA * 128);
        uint4 b = *(const uint4*)(Xs + (size_t)sB * 128);
        addv(a); addv(b);
    }
    if (j + 7 < end) {
        int sA = colv[j + grp];
        uint4 a = *(const uint4*)(Xs + (size_t)sA * 128);
        addv(a);
        j += 8;
    }
    int rem = end - j;
    if (rem > 0) {
        int sA = colv[j + (grp < rem ? grp : 0)];
        uint4 a = *(const uint4*)(Xs + (size_t)sA * 128);
        if (grp < rem) addv(a);
    }

#pragma unroll
    for (int c = 0; c < 16; c++) {
        acc[c] += __shfl_xor(acc[c], 8);
        acc[c] += __shfl_xor(acc[c], 16);
        acc[c] += __shfl_xor(acc[c], 32);
    }

    if (grp == 0) {
        float sc = invd[node];
        uint4 o0, o1;
        o0.x = pbf2(acc[0], acc[1], sc);   o0.y = pbf2(acc[2], acc[3], sc);
        o0.z = pbf2(acc[4], acc[5], sc);   o0.w = pbf2(acc[6], acc[7], sc);
        o1.x = pbf2(acc[8], acc[9], sc);   o1.y = pbf2(acc[10], acc[11], sc);
        o1.z = pbf2(acc[12], acc[13], sc); o1.w = pbf2(acc[14], acc[15], sc);
        short* op = out + (size_t)node * 128 + sub * 16;
        *(uint4*)op = o0;
        *(uint4*)(op + 8) = o1;
    }
}

// ---------------------------------------------------------------------------
// LDS-free dual-A bf16 MFMA GEMM; optional fp8 relu copy C8 for the next gather.
// 32-row blocks, acc[2][4]; k-loop unrolled x2 with distance-2 pair prefetch:
// 12 loads (16B each) issued per iteration ahead of 16 back-to-back MFMAs
// to raise memory-level parallelism (Little's law: was ~6 loads in flight
// at ~2 TB/s; target ~12).
__launch_bounds__(256, 3)
__global__ void k_gemm_mfma_wide(const short* __restrict__ A1, const short* A2,
                                 const short* __restrict__ P1, const short* __restrict__ P2,
                                 const float* __restrict__ bias,
                                 float* Cf, short* Cb, unsigned char* C8,
                                 int M, int K1, int K2) {
    const int lane = threadIdx.x & 63;
    const int wave = threadIdx.x >> 6;
    const int quad = lane >> 4;
    const int r    = lane & 15;
    const int rowBase = blockIdx.x * 32;

    f32x4 acc[2][4];
#pragma unroll
    for (int mt = 0; mt < 2; mt++)
#pragma unroll
        for (int nt = 0; nt < 4; nt++) acc[mt][nt] = (f32x4)(0.f);

    int arow[2];
#pragma unroll
    for (int mt = 0; mt < 2; mt++) {
        int row = rowBase + mt * 16 + r;
        arow[mt] = row < M ? row : M - 1;
    }

    for (int src = 0; src < 2; src++) {
        const short* A = src ? A2 : A1;
        const short* P = src ? P2 : P1;
        const int K = src ? K2 : K1;
        const int nks = K >> 5;   // K is a multiple of 64 here -> nks even

        bf16x8 a0[2], a1[2], b0[4], b1[4];
#pragma unroll
        for (int mt = 0; mt < 2; mt++) {
            a0[mt] = *(const bf16x8*)(A + (size_t)arow[mt] * K + quad * 8);
            a1[mt] = *(const bf16x8*)(A + (size_t)arow[mt] * K + 32 + quad * 8);
        }
#pragma unroll
        for (int nt = 0; nt < 4; nt++) {
            b0[nt] = *(const bf16x8*)(P + (((size_t)(wave * 4 + nt) * 64 + lane) << 3));
            b1[nt] = *(const bf16x8*)(P + (((size_t)(16 + wave * 4 + nt) * 64 + lane) << 3));
        }

        for (int ks = 0; ks < nks; ks += 2) {
            const int kp = (ks + 2 < nks) ? ks + 2 : ks;  // tail: cheap re-load
            bf16x8 a2[2], a3[2], b2[4], b3[4];
#pragma unroll
            for (int mt = 0; mt < 2; mt++) {
                a2[mt] = *(const bf16x8*)(A + (size_t)arow[mt] * K + kp * 32 + quad * 8);
                a3[mt] = *(const bf16x8*)(A + (size_t)arow[mt] * K + (kp + 1) * 32 + quad * 8);
            }
#pragma unroll
            for (int nt = 0; nt < 4; nt++) {
                b2[nt] = *(const bf16x8*)(P + (((size_t)(kp * 16 + wave * 4 + nt) * 64 + lane) << 3));
                b3[nt] = *(const bf16x8*)(P + (((size_t)((kp + 1) * 16 + wave * 4 + nt) * 64 + lane) << 3));
            }
#pragma unroll
            for (int mt = 0; mt < 2; mt++)
#pragma unroll
                for (int nt = 0; nt < 4; nt++)
                    acc[mt][nt] = __builtin_amdgcn_mfma_f32_16x16x32_bf16(
                        a0[mt], b0[nt], acc[mt][nt], 0, 0, 0);
#pragma unroll
            for (int mt = 0; mt < 2; mt++)
#pragma unroll
                for (int nt = 0; nt < 4; nt++)
                    acc[mt][nt] = __builtin_amdgcn_mfma_f32_16x16x32_bf16(
                        a1[mt], b1[nt], acc[mt][nt], 0, 0, 0);
#pragma unroll
            for (int mt = 0; mt < 2; mt++) { a0[mt] = a2[mt]; a1[mt] = a3[mt]; }
#pragma unroll
            for (int nt = 0; nt < 4; nt++) { b0[nt] = b2[nt]; b1[nt] = b3[nt]; }
        }
    }

    __syncthreads();  // guard in-place Cb == A2 (block reads/writes only its own rows)

    float bv[4];
#pragma unroll
    for (int nt = 0; nt < 4; nt++) bv[nt] = bias[wave * 64 + nt * 16 + r];

#pragma unroll
    for (int mt = 0; mt < 2; mt++) {
#pragma unroll
        for (int reg = 0; reg < 4; reg++) {
            int row = rowBase + mt * 16 + quad * 4 + reg;
            if (row >= M) continue;
#pragma unroll
            for (int nt = 0; nt < 4; nt++) {
                int col = wave * 64 + nt * 16 + r;
                float v = acc[mt][nt][reg] + bv[nt];
                if (Cf) Cf[(size_t)row * 256 + col] = v;
                if (Cb) Cb[(size_t)row * 256 + col] = f2bf(fmaxf(v, 0.f));
                if (C8) C8[(size_t)row * 256 + col] = enc1(fmaxf(v, 0.f));
            }
        }
    }
}

// Layer-2 fused dual-W MFMA: U (fp8, stride 48) + Out (fp32, [M,47]).
// Per-wave 32 rows (acc 2x3x2) + distance-1 A prefetch (P is 24KB, L1-hot).
__launch_bounds__(256, 4)
__global__ void k_gemm_mfma_out(const short* __restrict__ A,
                                const short* __restrict__ Pl, const short* __restrict__ Pr,
                                const float* __restrict__ bias,
                                unsigned char* __restrict__ U8, float* __restrict__ Out, int M) {
    const int lane = threadIdx.x & 63;
    const int wave = threadIdx.x >> 6;
    const int quad = lane >> 4;
    const int r    = lane & 15;
    const int rowBase = blockIdx.x * 128 + wave * 32;

    f32x4 aU[2][3], aO[2][3];
#pragma unroll
    for (int mt = 0; mt < 2; mt++)
#pragma unroll
        for (int nt = 0; nt < 3; nt++) { aU[mt][nt] = (f32x4)(0.f); aO[mt][nt] = (f32x4)(0.f); }

    int arow[2];
#pragma unroll
    for (int mt = 0; mt < 2; mt++) {
        int row = rowBase + mt * 16 + r;
        arow[mt] = row < M ? row : M - 1;
    }

    bf16x8 af[2];
#pragma unroll
    for (int mt = 0; mt < 2; mt++)
        af[mt] = *(const bf16x8*)(A + (size_t)arow[mt] * 256 + quad * 8);

    for (int ks = 0; ks < 8; ks++) {
        const int ksn = (ks + 1 < 8) ? ks + 1 : ks;
        bf16x8 afn[2], bl[3], br[3];
#pragma unroll
        for (int mt = 0; mt < 2; mt++)
            afn[mt] = *(const bf16x8*)(A + (size_t)arow[mt] * 256 + ksn * 32 + quad * 8);
#pragma unroll
        for (int nt = 0; nt < 3; nt++) {
            size_t fo = (((size_t)(ks * 3 + nt) * 64 + lane) << 3);
            bl[nt] = *(const bf16x8*)(Pl + fo);
            br[nt] = *(const bf16x8*)(Pr + fo);
        }
#pragma unroll
        for (int mt = 0; mt < 2; mt++)
#pragma unroll
            for (int nt = 0; nt < 3; nt++) {
                aU[mt][nt] = __builtin_amdgcn_mfma_f32_16x16x32_bf16(af[mt], bl[nt], aU[mt][nt], 0, 0, 0);
                aO[mt][nt] = __builtin_amdgcn_mfma_f32_16x16x32_bf16(af[mt], br[nt], aO[mt][nt], 0, 0, 0);
            }
#pragma unroll
        for (int mt = 0; mt < 2; mt++) af[mt] = afn[mt];
    }

    float bv[3];
#pragma unroll
    for (int nt = 0; nt < 3; nt++) {
        int col = nt * 16 + r;
        bv[nt] = (col < DOUT) ? bias[col] : 0.f;
    }

#pragma unroll
    for (int mt = 0; mt < 2; mt++) {
#pragma unroll
        for (int reg = 0; reg < 4; reg++) {
            int row = rowBase + mt * 16 + quad * 4 + reg;
            if (row >= M) continue;
#pragma unroll
            for (int nt = 0; nt < 3; nt++) {
                int col = nt * 16 + r;
                U8[(size_t)row * 48 + col] = enc1(aU[mt][nt][reg]);
                if (col < DOUT) Out[(size_t)row * DOUT + col] = aO[mt][nt][reg] + bv[nt];
            }
        }
    }
}

// out0[dst,:] += inv_deg[dst] * mean-agg of U8 rows (fp8, stride 48).
__launch_bounds__(256)
__global__ void k_agg_add47_f8(const unsigned char* __restrict__ U8, const int* __restrict__ rowptr,
                               const int* __restrict__ colv, const float* __restrict__ invd,
                               float* __restrict__ out0, int N) {
    const int lane = threadIdx.x & 63;
    const int node = blockIdx.x * 4 + (threadIdx.x >> 6);
    if (node >= N) return;
    int beg = __builtin_amdgcn_readfirstlane(rowptr[node]);
    int end = __builtin_amdgcn_readfirstlane(rowptr[node + 1]);
    const int q = lane >> 4, sub = lane & 15;
    const bool act = sub < 12;
    const unsigned char* Us = U8 + sub * 4;

    float acc[4] = {0.f, 0.f, 0.f, 0.f};

    int j = beg;
    for (; j + 7 < end; j += 8) {
        int i0 = colv[j], i1 = colv[j + 1], i2 = colv[j + 2], i3 = colv[j + 3];
        int i4 = colv[j + 4], i5 = colv[j + 5], i6 = colv[j + 6], i7 = colv[j + 7];
        int sA = (q == 0) ? i0 : (q == 1) ? i1 : (q == 2) ? i2 : i3;
        int sB = (q == 0) ? i4 : (q == 1) ? i5 : (q == 2) ? i6 : i7;
        if (act) {
            unsigned a = *(const unsigned*)(Us + (size_t)sA * 48);
            unsigned b = *(const unsigned*)(Us + (size_t)sB * 48);
            addpk(a, acc); addpk(b, acc);
        }
    }
    if (j + 3 < end) {
        int i0 = colv[j], i1 = colv[j + 1], i2 = colv[j + 2], i3 = colv[j + 3];
        int sA = (q == 0) ? i0 : (q == 1) ? i1 : (q == 2) ? i2 : i3;
        if (act) {
            unsigned a = *(const unsigned*)(Us + (size_t)sA * 48);
            addpk(a, acc);
        }
        j += 4;
    }
    int rem = end - j;
    if (rem > 0) {
        int i0 = colv[j];
        int i1 = rem > 1 ? colv[j + 1] : i0;
        int i2 = rem > 2 ? colv[j + 2] : i0;
        int s = (q == 1) ? i1 : (q == 2) ? i2 : i0;
        if (act && q < rem) {
            unsigned a = *(const unsigned*)(Us + (size_t)s * 48);
            addpk(a, acc);
        }
    }

#pragma unroll
    for (int c = 0; c < 4; c++) {
        acc[c] += __shfl_xor(acc[c], 16);
        acc[c] += __shfl_xor(acc[c], 32);
    }

    if (q == 0 && act) {
        float sc = invd[node];
        int f0 = sub * 4;
        float* op = out0 + (size_t)node * DOUT;
#pragma unroll
        for (int c = 0; c < 4; c++)
            if (f0 + c < DOUT) op[f0 + c] += sc * acc[c];
    }
}

// ---------------------------------------------------------------------------
extern "C" void kernel_launch(void* const* d_in, const int* in_sizes, int n_in,
                              void* d_out, int out_size, void* d_ws, size_t ws_size,
                              hipStream_t stream) {
    const float* x   = (const float*)d_in[0];
    const int*   ei  = (const int*)d_in[1];
    const float* Wl0 = (const float*)d_in[2];
    const float* bl0 = (const float*)d_in[3];
    const float* Wr0 = (const float*)d_in[4];
    const float* Wl1 = (const float*)d_in[5];
    const float* bl1 = (const float*)d_in[6];
    const float* Wr1 = (const float*)d_in[7];
    const float* Wl2 = (const float*)d_in[8];
    const float* bl2 = (const float*)d_in[9];
    const float* Wr2 = (const float*)d_in[10];

    const int N = in_sizes[0] / DIN;
    const int E = in_sizes[1] / 2;

    char* p = (char*)d_ws;
    auto alloc = [&](size_t bytes) -> char* {
        char* r = p;
        p += (bytes + 255) & ~(size_t)255;
        return r;
    };
    int*   flag   = (int*)alloc(4);
    int*   cnt    = (int*)alloc((size_t)N * 4);
    int*   rowptr = (int*)alloc((size_t)(N + 1) * 4);
    int*   csum   = (int*)alloc(1024 * 4);
    int*   colbuf = (int*)alloc((size_t)E * 4 + 64);
    float* invd   = (float*)alloc((size_t)N * 4);
    int*   bucketCnt = (int*)alloc(1025 * 4);
    int*   bucketOff = (int*)alloc(1025 * 4);
    int*   bucketCur = (int*)alloc(1024 * 4);
    short* xbf    = (short*)alloc((size_t)N * DIN * 2);   // x bf16; later reused as U8 [N,48] fp8
    short* bufA   = (short*)alloc((size_t)N * DH * 2);    // agg output (bf16); pre-agg: pairbuf
    short* h0     = (short*)alloc((size_t)N * DH * 2);    // h0 bf16; hrelu in-place after L1
    unsigned*      x8 = (unsigned*)alloc((size_t)N * DIN);      // fp8 x (gather table)
    unsigned char* h8 = (unsigned char*)alloc((size_t)N * DH);  // fp8 relu(h0) (gather table)
    short* Pl0    = (short*)alloc((size_t)DIN * 256 * 2);
    short* Pr0    = (short*)alloc((size_t)DIN * 256 * 2);
    short* Pl1    = (short*)alloc((size_t)DH * 256 * 2);
    short* Pr1    = (short*)alloc((size_t)DH * 256 * 2);
    short* Pl2    = (short*)alloc((size_t)DH * 48 * 2);
    short* Pr2    = (short*)alloc((size_t)DH * 48 * 2);

    float* out0 = (float*)d_out;                        // [N,47]
    float* hout = (float*)d_out + (size_t)N * DOUT;     // [N,256] fp32 (output 1)

    // Bucketed CSR parameters: smallest span >= 128 with <= 1024 buckets.
    int span_shift = 7;
    while ((((N - 1) >> span_shift) + 1) > 1024 && span_shift < 21) span_shift++;
    const int NBK = ((N - 1) >> span_shift) + 1;
    const bool fast_csr = (NBK <= 1024) && ((1 << span_shift) <= 2048) &&
                          ((size_t)E * 8 <= (size_t)N * DH * 2);
    uint2* pairbuf = (uint2*)bufA;  // bufA dead until L0 agg

    hipMemsetAsync(flag, 0, 4, stream);
    hipMemsetAsync(cnt, 0, (size_t)N * 4, stream);
    hipMemsetAsync(bucketCnt, 0, (size_t)NBK * 4, stream);

    // --- CSR build ---
    const int nprobe = E < 4096 ? E : 4096;
    k_detect<<<(nprobe + 255) / 256, 256, 0, stream>>>(ei, flag, nprobe);
    if (fast_csr) {
        k_binhist<<<256, 256, 0, stream>>>(ei, flag, bucketCnt, E, span_shift, NBK);
        k_bucket_scan<<<1, 1024, 0, stream>>>(bucketCnt, bucketOff, bucketCur, NBK, E);
        k_binscatter<<<256, 256, 0, stream>>>(ei, flag, bucketOff, bucketCur, pairbuf, E, span_shift, NBK);
        k_bhist<<<NBK, 256, 0, stream>>>(pairbuf, bucketOff, cnt, span_shift, N);
    } else {
        k_hist<<<(E + 255) / 256, 256, 0, stream>>>(ei, flag, cnt, E);
    }
    const int nchunks = (N + 1023) / 1024;
    k_chunk_sum<<<nchunks, 256, 0, stream>>>(cnt, csum, N);
    k_scan_csum<<<1, 128, 0, stream>>>(csum, nchunks, rowptr, N, E);
    k_scan_apply<<<nchunks, 256, 0, stream>>>(cnt, csum, rowptr, N);
    hipMemsetAsync(cnt, 0, (size_t)N * 4, stream);
    if (fast_csr) {
        k_fill2<<<NBK, 256, 0, stream>>>(pairbuf, bucketOff, rowptr, cnt, colbuf, span_shift, N);
    } else {
        k_fill<<<(E + 255) / 256, 256, 0, stream>>>(ei, flag, rowptr, cnt, colbuf, E);
    }
    k_invdeg<<<(N + 255) / 256, 256, 0, stream>>>(rowptr, invd, N);

    // --- weight packing + x conversion ---
    k_pack<<<(4 * 16 * 64 + 255) / 256, 256, 0, stream>>>(Wl0, Pl0, 4, 16, 256);
    k_pack<<<(4 * 16 * 64 + 255) / 256, 256, 0, stream>>>(Wr0, Pr0, 4, 16, 256);
    k_pack<<<(8 * 16 * 64 + 255) / 256, 256, 0, stream>>>(Wl1, Pl1, 8, 16, 256);
    k_pack<<<(8 * 16 * 64 + 255) / 256, 256, 0, stream>>>(Wr1, Pr1, 8, 16, 256);
    k_pack<<<(8 * 3 * 64 + 255) / 256, 256, 0, stream>>>(Wl2, Pl2, 8, 3, DOUT);
    k_pack<<<(8 * 3 * 64 + 255) / 256, 256, 0, stream>>>(Wr2, Pr2, 8, 3, DOUT);
    k_f2bf8<<<((N * DIN / 4) + 255) / 256, 256, 0, stream>>>(x, xbf, x8, N * DIN / 4);

    const int aggBlocks = (N + 3) / 4;
    const int gw = (N + 31) / 32;

    // Layer 0: h0 = bf16(relu(...)), h8 = fp8(relu(...))
    k_agg128_f8<<<aggBlocks, 256, 0, stream>>>((const unsigned char*)x8, rowptr, colbuf, invd, bufA, N);
    k_gemm_mfma_wide<<<gw, 256, 0, stream>>>(bufA, xbf, Pl0, Pr0, bl0,
                                             nullptr, h0, h8, N, DIN, DIN);

    // Layer 1: hout fp32 (output 1); hrelu bf16 in-place over h0
    k_agg256_f8<<<aggBlocks, 256, 0, stream>>>(h8, rowptr, colbuf, invd, bufA, N);
    k_gemm_mfma_wide<<<gw, 256, 0, stream>>>(bufA, h0, Pl1, Pr1, bl1,
                                             hout, h0, nullptr, N, DH, DH);

    // Layer 2: U8 = fp8(hrelu@Wl2), out0 = hrelu@Wr2 + bl2; out0 += agg(U8)
    unsigned char* U8 = (unsigned char*)xbf;  // xbf dead after L0 GEMM
    k_gemm_mfma_out<<<(N + 127) / 128, 256, 0, stream>>>(h0, Pl2, Pr2, bl2, U8, out0, N);
    k_agg_add47_f8<<<aggBlocks, 256, 0, stream>>>(U8, rowptr, colbuf, invd, out0, N);
}

// Round 6
// 610.660 us; speedup vs baseline: 1.0523x; 1.0523x over previous
//
#include <hip/hip_runtime.h>
#include <cstdint>
#include <cstddef>

static constexpr int DIN  = 128;
static constexpr int DH   = 256;
static constexpr int DOUT = 47;

typedef __attribute__((ext_vector_type(8))) short bf16x8;
typedef __attribute__((ext_vector_type(4))) float f32x4;
typedef __attribute__((ext_vector_type(2))) float f32x2;

__device__ __forceinline__ short f2bf(float f) {
    unsigned u = __float_as_uint(f);
    unsigned r = (u + 0x7fffu + ((u >> 16) & 1u)) >> 16;  // RNE
    return (short)r;
}

// fp8 e4m3 (HW-native) helpers
__device__ __forceinline__ void addpk(unsigned w, float* a) {
    f32x2 lo = __builtin_amdgcn_cvt_pk_f32_fp8(w, false);
    f32x2 hi = __builtin_amdgcn_cvt_pk_f32_fp8(w, true);
    a[0] += lo[0]; a[1] += lo[1]; a[2] += hi[0]; a[3] += hi[1];
}
__device__ __forceinline__ unsigned enc4(float a, float b, float c, float d) {
    unsigned w = __builtin_amdgcn_cvt_pk_fp8_f32(a, b, 0, false);
    w = __builtin_amdgcn_cvt_pk_fp8_f32(c, d, w, true);
    return w;
}
__device__ __forceinline__ unsigned char enc1(float v) {
    return (unsigned char)(__builtin_amdgcn_cvt_pk_fp8_f32(v, v, 0, false) & 0xff);
}
__device__ __forceinline__ unsigned pbf2(float a, float b, float sc) {
    return (unsigned)(unsigned short)f2bf(a * sc) |
           ((unsigned)(unsigned short)f2bf(b * sc) << 16);
}

// A-fragment layout: value A[row][k] lives at
//   ((tile*nks + ks)*64 + q*16 + r)*8 + j   (shorts)
// with tile=row>>4, r=row&15, ks=k>>5, q=(k>>3)&3, j=k&7.
// A wave's load of one (tile,ks) fragment is 64 lanes x 16B contiguous.

// ---------------------------------------------------------------------------
// CSR build
__global__ void k_detect(const int* __restrict__ e, int* __restrict__ flag, int nprobe) {
    int i = blockIdx.x * blockDim.x + threadIdx.x;
    if (i < nprobe) {
        if (e[2 * i + 1] != 0) atomicOr(flag, 1);
    }
}

// Legacy fallback path (used only when bucket params don't fit)
__global__ void k_hist(const int* __restrict__ e, const int* __restrict__ flag,
                       int* __restrict__ cnt, int E) {
    int i = blockIdx.x * blockDim.x + threadIdx.x;
    if (i >= E) return;
    int is32 = *flag;
    int d = is32 ? e[E + i] : e[2 * (E + i)];
    atomicAdd(&cnt[d], 1);
}

__global__ void k_fill(const int* __restrict__ e, const int* __restrict__ flag,
                       const int* __restrict__ rowptr, int* __restrict__ cursor,
                       int* __restrict__ colbuf, int E) {
    int i = blockIdx.x * blockDim.x + threadIdx.x;
    if (i >= E) return;
    int is32 = *flag;
    int s = is32 ? e[i] : e[2 * i];
    int d = is32 ? e[E + i] : e[2 * (E + i)];
    int pos = atomicAdd(&cursor[d], 1);
    colbuf[rowptr[d] + pos] = s;
}

// --- Fast bucketed CSR build ------------------------------------------------
__launch_bounds__(256)
__global__ void k_binhist(const int* __restrict__ e, const int* __restrict__ flag,
                          int* __restrict__ bucketCnt, int E, int shift, int nbk) {
    __shared__ int h[1024];
    int t = threadIdx.x;
    for (int i = t; i < nbk; i += 256) h[i] = 0;
    __syncthreads();
    int is32 = *flag;
    int stride = gridDim.x * 256;
    for (int i = blockIdx.x * 256 + t; i < E; i += stride) {
        int d = is32 ? e[E + i] : e[2 * (E + i)];
        atomicAdd(&h[d >> shift], 1);
    }
    __syncthreads();
    for (int i = t; i < nbk; i += 256) {
        int v = h[i];
        if (v) atomicAdd(&bucketCnt[i], v);
    }
}

__global__ void k_bucket_scan(const int* __restrict__ bucketCnt, int* __restrict__ bucketOff,
                              int* __restrict__ bucketCur, int nbk, int E) {
    __shared__ int s[1024];
    int t = threadIdx.x;
    int v = (t < nbk) ? bucketCnt[t] : 0;
    s[t] = v;
    __syncthreads();
    for (int off = 1; off < 1024; off <<= 1) {
        int xv = (t >= off) ? s[t - off] : 0;
        __syncthreads();
        s[t] += xv;
        __syncthreads();
    }
    if (t < nbk) { bucketOff[t] = s[t] - v; bucketCur[t] = 0; }
    if (t == 0) bucketOff[nbk] = E;
}

__launch_bounds__(256)
__global__ void k_binscatter(const int* __restrict__ e, const int* __restrict__ flag,
                             const int* __restrict__ bucketOff, int* __restrict__ bucketCur,
                             uint2* __restrict__ pairbuf, int E, int shift, int nbk) {
    __shared__ int h[1024];
    __shared__ int cur[1024];
    int t = threadIdx.x;
    for (int i = t; i < nbk; i += 256) h[i] = 0;
    __syncthreads();
    int is32 = *flag;
    int chunk = (E + gridDim.x - 1) / gridDim.x;
    int lo = blockIdx.x * chunk;
    int hi = lo + chunk < E ? lo + chunk : E;
    for (int i = lo + t; i < hi; i += 256) {
        int d = is32 ? e[E + i] : e[2 * (E + i)];
        atomicAdd(&h[d >> shift], 1);
    }
    __syncthreads();
    for (int i = t; i < nbk; i += 256) {
        int c = h[i];
        int base = c ? atomicAdd(&bucketCur[i], c) : 0;
        h[i] = bucketOff[i] + base;
        cur[i] = 0;
    }
    __syncthreads();
    for (int i = lo + t; i < hi; i += 256) {
        int sv = is32 ? e[i] : e[2 * i];
        int d  = is32 ? e[E + i] : e[2 * (E + i)];
        int b = d >> shift;
        int lp = atomicAdd(&cur[b], 1);
        pairbuf[h[b] + lp] = make_uint2((unsigned)sv, (unsigned)d);
    }
}

__launch_bounds__(256)
__global__ void k_bhist(const uint2* __restrict__ pairbuf, const int* __restrict__ bucketOff,
                        int* __restrict__ cnt, int shift, int N) {
    __shared__ int h[2048];
    int b = blockIdx.x;
    int t = threadIdx.x;
    int first = b << shift;
    int span = (1 << shift);
    if (first + span > N) span = N - first;
    for (int i = t; i < span; i += 256) h[i] = 0;
    __syncthreads();
    int lo = bucketOff[b], hi = bucketOff[b + 1];
    for (int j = lo + t; j < hi; j += 256) {
        int d = (int)pairbuf[j].y;
        atomicAdd(&h[d - first], 1);
    }
    __syncthreads();
    for (int i = t; i < span; i += 256) cnt[first + i] = h[i];
}

#define FILL_CAP 12288
__launch_bounds__(256)
__global__ void k_fill2(const uint2* __restrict__ pairbuf, const int* __restrict__ bucketOff,
                        const int* __restrict__ rowptr, int* __restrict__ cursor,
                        int* __restrict__ colbuf, int shift, int N) {
    __shared__ int cur[2048];
    __shared__ int sbuf[FILL_CAP];
    int b = blockIdx.x;
    int t = threadIdx.x;
    int first = b << shift;
    int span = (1 << shift);
    if (first + span > N) span = N - first;
    int lo = bucketOff[b], hi = bucketOff[b + 1];
    int nEdge = hi - lo;
    int base = rowptr[first];
    if (nEdge <= FILL_CAP) {
        for (int i = t; i < span; i += 256) cur[i] = rowptr[first + i] - base;
        __syncthreads();
        for (int j = lo + t; j < hi; j += 256) {
            uint2 p = pairbuf[j];
            int lp = atomicAdd(&cur[(int)p.y - first], 1);
            sbuf[lp] = (int)p.x;
        }
        __syncthreads();
        for (int i = t; i < nEdge; i += 256) colbuf[base + i] = sbuf[i];
    } else {
        for (int j = lo + t; j < hi; j += 256) {
            uint2 p = pairbuf[j];
            int d = (int)p.y;
            int pos = atomicAdd(&cursor[d], 1);
            colbuf[rowptr[d] + pos] = (int)p.x;
        }
    }
}

__global__ void k_chunk_sum(const int* __restrict__ cnt, int* __restrict__ csum, int n) {
    int base = blockIdx.x * 1024;
    int t = threadIdx.x;
    int s = 0;
#pragma unroll
    for (int j = 0; j < 4; j++) {
        int i = base + t * 4 + j;
        if (i < n) s += cnt[i];
    }
    __shared__ int red[256];
    red[t] = s;
    __syncthreads();
    for (int off = 128; off > 0; off >>= 1) {
        if (t < off) red[t] += red[t + off];
        __syncthreads();
    }
    if (t == 0) csum[blockIdx.x] = red[0];
}

__global__ void k_scan_csum(int* __restrict__ csum, int n,
                            int* __restrict__ rowptr, int N, int E) {
    __shared__ int s[128];
    int t = threadIdx.x;
    int v = (t < n) ? csum[t] : 0;
    s[t] = v;
    __syncthreads();
    for (int off = 1; off < 128; off <<= 1) {
        int xv = (t >= off) ? s[t - off] : 0;
        __syncthreads();
        s[t] += xv;
        __syncthreads();
    }
    if (t < n) csum[t] = s[t] - v;  // exclusive
    if (t == 0) rowptr[N] = E;
}

__global__ void k_scan_apply(const int* __restrict__ cnt, const int* __restrict__ csum,
                             int* __restrict__ rowptr, int n) {
    int base = blockIdx.x * 1024, t = threadIdx.x;
    int i0 = base + t * 4;
    int v[4];
#pragma unroll
    for (int j = 0; j < 4; j++) {
        int i = i0 + j;
        v[j] = (i < n) ? cnt[i] : 0;
    }
    int tsum = v[0] + v[1] + v[2] + v[3];
    __shared__ int s[256];
    s[t] = tsum;
    __syncthreads();
    for (int off = 1; off < 256; off <<= 1) {
        int xv = (t >= off) ? s[t - off] : 0;
        __syncthreads();
        s[t] += xv;
        __syncthreads();
    }
    int excl = s[t] - tsum + csum[blockIdx.x];
#pragma unroll
    for (int j = 0; j < 4; j++) {
        int i = i0 + j;
        if (i < n) rowptr[i] = excl;
        excl += v[j];
    }
}

__global__ void k_invdeg(const int* __restrict__ rowptr, float* __restrict__ invd, int N) {
    int i = blockIdx.x * blockDim.x + threadIdx.x;
    if (i >= N) return;
    int d = rowptr[i + 1] - rowptr[i];
    invd[i] = 1.0f / (float)(d > 1 ? d : 1);
}

// ---------------------------------------------------------------------------
// fp32 x -> bf16 A-fragments (GEMM A2, nks=4) + fp8 row-major (gather table).
// One thread per 8-element fragment word.
__global__ void k_f2bf8(const float* __restrict__ X, short* __restrict__ Yb,
                        unsigned* __restrict__ Y8, int nTiles, int N) {
    int t = blockIdx.x * 256 + threadIdx.x;
    int total = nTiles * 4 * 64;
    if (t >= total) return;
    int lane = t & 63;
    int kt = t >> 6;          // tile*4 + ks
    int ks = kt & 3;
    int tile = kt >> 2;
    int q = (lane >> 4) & 3;
    int r = lane & 15;
    int row = tile * 16 + r;
    int col = ks * 32 + q * 8;
    bf16x8 o = (bf16x8)(short)0;
    if (row < N) {
        const float* src = X + (size_t)row * DIN + col;
        float4 v0 = *(const float4*)src;
        float4 v1 = *(const float4*)(src + 4);
        o[0] = f2bf(v0.x); o[1] = f2bf(v0.y); o[2] = f2bf(v0.z); o[3] = f2bf(v0.w);
        o[4] = f2bf(v1.x); o[5] = f2bf(v1.y); o[6] = f2bf(v1.z); o[7] = f2bf(v1.w);
        unsigned* p8 = Y8 + ((size_t)row * DIN + col) / 4;
        p8[0] = enc4(v0.x, v0.y, v0.z, v0.w);
        p8[1] = enc4(v1.x, v1.y, v1.z, v1.w);
    }
    *(bf16x8*)(Yb + (size_t)t * 8) = o;
}

// Pack fp32 weight [K, Ncols] into bf16 B-fragment order for mfma_16x16x32
__global__ void k_pack(const float* __restrict__ W, short* __restrict__ P,
                       int ksteps, int Nt, int Ncols) {
    int idx = blockIdx.x * 256 + threadIdx.x;
    int total = ksteps * Nt * 64;
    if (idx >= total) return;
    int lane = idx & 63;
    int t = idx >> 6;
    int nt = t % Nt;
    int ks = t / Nt;
    int n = nt * 16 + (lane & 15);
    int kb = ks * 32 + (lane >> 4) * 8;
    bf16x8 o;
#pragma unroll
    for (int j = 0; j < 8; j++)
        o[j] = (n < Ncols) ? f2bf(W[(size_t)(kb + j) * Ncols + n]) : (short)0;
    *(bf16x8*)(P + (size_t)idx * 8) = o;
}

// ---------------------------------------------------------------------------
// 256-wide fp8 CSR mean-agg. Output: bf16 A-fragments (nks=8).
__launch_bounds__(256)
__global__ void k_agg256_f8(const unsigned char* __restrict__ X8, const int* __restrict__ rowptr,
                            const int* __restrict__ colv, const float* __restrict__ invd,
                            short* __restrict__ out, int N) {
    const int lane = threadIdx.x & 63;
    const int node = blockIdx.x * 4 + (threadIdx.x >> 6);
    if (node >= N) return;
    int beg = __builtin_amdgcn_readfirstlane(rowptr[node]);
    int end = __builtin_amdgcn_readfirstlane(rowptr[node + 1]);
    const int q = lane >> 4, sub = lane & 15;
    const unsigned char* Xs = X8 + sub * 16;

    float acc[16];
#pragma unroll
    for (int c = 0; c < 16; c++) acc[c] = 0.f;

    auto addv = [&](uint4 a) {
        addpk(a.x, acc); addpk(a.y, acc + 4); addpk(a.z, acc + 8); addpk(a.w, acc + 12);
    };

    int j = beg;
    for (; j + 7 < end; j += 8) {
        int i0 = colv[j], i1 = colv[j + 1], i2 = colv[j + 2], i3 = colv[j + 3];
        int i4 = colv[j + 4], i5 = colv[j + 5], i6 = colv[j + 6], i7 = colv[j + 7];
        int sA = (q == 0) ? i0 : (q == 1) ? i1 : (q == 2) ? i2 : i3;
        int sB = (q == 0) ? i4 : (q == 1) ? i5 : (q == 2) ? i6 : i7;
        uint4 a = *(const uint4*)(Xs + (size_t)sA * 256);
        uint4 b = *(const uint4*)(Xs + (size_t)sB * 256);
        addv(a); addv(b);
    }
    if (j + 3 < end) {
        int i0 = colv[j], i1 = colv[j + 1], i2 = colv[j + 2], i3 = colv[j + 3];
        int sA = (q == 0) ? i0 : (q == 1) ? i1 : (q == 2) ? i2 : i3;
        uint4 a = *(const uint4*)(Xs + (size_t)sA * 256);
        addv(a);
        j += 4;
    }
    int rem = end - j;
    if (rem > 0) {
        int i0 = colv[j];
        int i1 = rem > 1 ? colv[j + 1] : i0;
        int i2 = rem > 2 ? colv[j + 2] : i0;
        int s = (q == 1) ? i1 : (q == 2) ? i2 : i0;
        uint4 a = *(const uint4*)(Xs + (size_t)s * 256);
        if (q < rem) addv(a);
    }

#pragma unroll
    for (int c = 0; c < 16; c++) {
        acc[c] += __shfl_xor(acc[c], 16);
        acc[c] += __shfl_xor(acc[c], 32);
    }

    if (q == 0) {
        float sc = invd[node];
        uint4 o0, o1;
        o0.x = pbf2(acc[0], acc[1], sc);   o0.y = pbf2(acc[2], acc[3], sc);
        o0.z = pbf2(acc[4], acc[5], sc);   o0.w = pbf2(acc[6], acc[7], sc);
        o1.x = pbf2(acc[8], acc[9], sc);   o1.y = pbf2(acc[10], acc[11], sc);
        o1.z = pbf2(acc[12], acc[13], sc); o1.w = pbf2(acc[14], acc[15], sc);
        // fragment dests: channels sub*16+0..7 -> (ks=sub>>1, q1), +8..15 -> q2
        const int tile = node >> 4, r = node & 15;
        const int ksC = sub >> 1, q1 = (sub & 1) * 2;
        size_t base = ((size_t)(tile * 8 + ksC) * 64 + r) * 8;
        *(uint4*)(out + base + (size_t)q1 * 128)       = o0;   // q1*16 lanes *8 shorts
        *(uint4*)(out + base + (size_t)(q1 + 1) * 128) = o1;
    }
}

// 128-wide fp8 CSR mean-agg. Output: bf16 A-fragments (nks=4).
__launch_bounds__(256)
__global__ void k_agg128_f8(const unsigned char* __restrict__ X8, const int* __restrict__ rowptr,
                            const int* __restrict__ colv, const float* __restrict__ invd,
                            short* __restrict__ out, int N) {
    const int lane = threadIdx.x & 63;
    const int node = blockIdx.x * 4 + (threadIdx.x >> 6);
    if (node >= N) return;
    int beg = __builtin_amdgcn_readfirstlane(rowptr[node]);
    int end = __builtin_amdgcn_readfirstlane(rowptr[node + 1]);
    const int grp = lane >> 3, sub = lane & 7;
    const unsigned char* Xs = X8 + sub * 16;

    float acc[16];
#pragma unroll
    for (int c = 0; c < 16; c++) acc[c] = 0.f;

    auto addv = [&](uint4 a) {
        addpk(a.x, acc); addpk(a.y, acc + 4); addpk(a.z, acc + 8); addpk(a.w, acc + 12);
    };

    int j = beg;
    for (; j + 15 < end; j += 16) {
        int sA = colv[j + grp];
        int sB = colv[j + 8 + grp];
        uint4 a = *(const uint4*)(Xs + (size_t)sA * 128);
        uint4 b = *(const uint4*)(Xs + (size_t)sB * 128);
        addv(a); addv(b);
    }
    if (j + 7 < end) {
        int sA = colv[j + grp];
        uint4 a = *(const uint4*)(Xs + (size_t)sA * 128);
        addv(a);
        j += 8;
    }
    int rem = end - j;
    if (rem > 0) {
        int sA = colv[j + (grp < rem ? grp : 0)];
        uint4 a = *(const uint4*)(Xs + (size_t)sA * 128);
        if (grp < rem) addv(a);
    }

#pragma unroll
    for (int c = 0; c < 16; c++) {
        acc[c] += __shfl_xor(acc[c], 8);
        acc[c] += __shfl_xor(acc[c], 16);
        acc[c] += __shfl_xor(acc[c], 32);
    }

    if (grp == 0) {
        float sc = invd[node];
        uint4 o0, o1;
        o0.x = pbf2(acc[0], acc[1], sc);   o0.y = pbf2(acc[2], acc[3], sc);
        o0.z = pbf2(acc[4], acc[5], sc);   o0.w = pbf2(acc[6], acc[7], sc);
        o1.x = pbf2(acc[8], acc[9], sc);   o1.y = pbf2(acc[10], acc[11], sc);
        o1.z = pbf2(acc[12], acc[13], sc); o1.w = pbf2(acc[14], acc[15], sc);
        const int tile = node >> 4, r = node & 15;
        const int ksC = sub >> 1, q1 = (sub & 1) * 2;
        size_t base = ((size_t)(tile * 4 + ksC) * 64 + r) * 8;
        *(uint4*)(out + base + (size_t)q1 * 128)       = o0;
        *(uint4*)(out + base + (size_t)(q1 + 1) * 128) = o1;
    }
}

// ---------------------------------------------------------------------------
// LDS-free dual-A bf16 MFMA GEMM; A in fragment order (lane-contiguous loads),
// dist-1 prefetch, acc[2][4], 32-row blocks. Cb written in fragment order
// (nks=8) for downstream consumers; Cf/C8 row-major.
__launch_bounds__(256, 4)
__global__ void k_gemm_mfma_wide(const short* __restrict__ A1, const short* A2,
                                 const short* __restrict__ P1, const short* __restrict__ P2,
                                 const float* __restrict__ bias,
                                 float* Cf, short* Cb, unsigned char* C8,
                                 int M, int K1, int K2) {
    const int lane = threadIdx.x & 63;
    const int wave = threadIdx.x >> 6;
    const int quad = lane >> 4;
    const int r    = lane & 15;
    const int rowBase = blockIdx.x * 32;
    const int tile0 = blockIdx.x * 2;

    f32x4 acc[2][4];
#pragma unroll
    for (int mt = 0; mt < 2; mt++)
#pragma unroll
        for (int nt = 0; nt < 4; nt++) acc[mt][nt] = (f32x4)(0.f);

    for (int src = 0; src < 2; src++) {
        const short* A = src ? A2 : A1;
        const short* P = src ? P2 : P1;
        const int K = src ? K2 : K1;
        const int nks = K >> 5;

        bf16x8 af[2], bfr[4];
#pragma unroll
        for (int mt = 0; mt < 2; mt++)
            af[mt] = *(const bf16x8*)(A + (((size_t)(tile0 + mt) * nks * 64 + lane) << 3));
#pragma unroll
        for (int nt = 0; nt < 4; nt++)
            bfr[nt] = *(const bf16x8*)(P + (((size_t)(wave * 4 + nt) * 64 + lane) << 3));

        for (int ks = 0; ks < nks; ks++) {
            const int ksn = (ks + 1 < nks) ? ks + 1 : ks;  // last iter: cheap re-load
            bf16x8 afn[2], bfn[4];
#pragma unroll
            for (int mt = 0; mt < 2; mt++)
                afn[mt] = *(const bf16x8*)(A + ((((size_t)(tile0 + mt) * nks + ksn) * 64 + lane) << 3));
#pragma unroll
            for (int nt = 0; nt < 4; nt++)
                bfn[nt] = *(const bf16x8*)(P + (((size_t)(ksn * 16 + wave * 4 + nt) * 64 + lane) << 3));
#pragma unroll
            for (int mt = 0; mt < 2; mt++)
#pragma unroll
                for (int nt = 0; nt < 4; nt++)
                    acc[mt][nt] = __builtin_amdgcn_mfma_f32_16x16x32_bf16(
                        af[mt], bfr[nt], acc[mt][nt], 0, 0, 0);
#pragma unroll
            for (int mt = 0; mt < 2; mt++) af[mt] = afn[mt];
#pragma unroll
            for (int nt = 0; nt < 4; nt++) bfr[nt] = bfn[nt];
        }
    }

    __syncthreads();  // guard in-place Cb == A2 (block touches only its own tiles)

    float bv[4];
#pragma unroll
    for (int nt = 0; nt < 4; nt++) bv[nt] = bias[wave * 64 + nt * 16 + r];

#pragma unroll
    for (int mt = 0; mt < 2; mt++) {
#pragma unroll
        for (int reg = 0; reg < 4; reg++) {
            int rC = quad * 4 + reg;
            int row = rowBase + mt * 16 + rC;
            if (row >= M) continue;
#pragma unroll
            for (int nt = 0; nt < 4; nt++) {
                int col = wave * 64 + nt * 16 + r;
                float v = acc[mt][nt][reg] + bv[nt];
                if (Cf) Cf[(size_t)row * 256 + col] = v;
                if (Cb) {
                    // fragment dest (nksC = 8)
                    int ksC = wave * 2 + (nt >> 1);
                    int qC  = (nt & 1) * 2 + (r >> 3);
                    size_t d = ((((size_t)(tile0 + mt) * 8 + ksC) * 64 + qC * 16 + rC) << 3) + (r & 7);
                    Cb[d] = f2bf(fmaxf(v, 0.f));
                }
                if (C8) C8[(size_t)row * 256 + col] = enc1(fmaxf(v, 0.f));
            }
        }
    }
}

// Layer-2 fused dual-W MFMA: U (fp8, stride 48) + Out (fp32, [M,47]).
// A in fragment order (nks=8), dist-1 A prefetch.
__launch_bounds__(256, 4)
__global__ void k_gemm_mfma_out(const short* __restrict__ A,
                                const short* __restrict__ Pl, const short* __restrict__ Pr,
                                const float* __restrict__ bias,
                                unsigned char* __restrict__ U8, float* __restrict__ Out, int M) {
    const int lane = threadIdx.x & 63;
    const int wave = threadIdx.x >> 6;
    const int quad = lane >> 4;
    const int r    = lane & 15;
    const int rowBase = blockIdx.x * 128 + wave * 32;
    const int tile0 = blockIdx.x * 8 + wave * 2;

    f32x4 aU[2][3], aO[2][3];
#pragma unroll
    for (int mt = 0; mt < 2; mt++)
#pragma unroll
        for (int nt = 0; nt < 3; nt++) { aU[mt][nt] = (f32x4)(0.f); aO[mt][nt] = (f32x4)(0.f); }

    bf16x8 af[2];
#pragma unroll
    for (int mt = 0; mt < 2; mt++)
        af[mt] = *(const bf16x8*)(A + (((size_t)(tile0 + mt) * 8 * 64 + lane) << 3));

    for (int ks = 0; ks < 8; ks++) {
        const int ksn = (ks + 1 < 8) ? ks + 1 : ks;
        bf16x8 afn[2], bl[3], br[3];
#pragma unroll
        for (int mt = 0; mt < 2; mt++)
            afn[mt] = *(const bf16x8*)(A + ((((size_t)(tile0 + mt) * 8 + ksn) * 64 + lane) << 3));
#pragma unroll
        for (int nt = 0; nt < 3; nt++) {
            size_t fo = (((size_t)(ks * 3 + nt) * 64 + lane) << 3);
            bl[nt] = *(const bf16x8*)(Pl + fo);
            br[nt] = *(const bf16x8*)(Pr + fo);
        }
#pragma unroll
        for (int mt = 0; mt < 2; mt++)
#pragma unroll
            for (int nt = 0; nt < 3; nt++) {
                aU[mt][nt] = __builtin_amdgcn_mfma_f32_16x16x32_bf16(af[mt], bl[nt], aU[mt][nt], 0, 0, 0);
                aO[mt][nt] = __builtin_amdgcn_mfma_f32_16x16x32_bf16(af[mt], br[nt], aO[mt][nt], 0, 0, 0);
            }
#pragma unroll
        for (int mt = 0; mt < 2; mt++) af[mt] = afn[mt];
    }

    float bv[3];
#pragma unroll
    for (int nt = 0; nt < 3; nt++) {
        int col = nt * 16 + r;
        bv[nt] = (col < DOUT) ? bias[col] : 0.f;
    }

#pragma unroll
    for (int mt = 0; mt < 2; mt++) {
#pragma unroll
        for (int reg = 0; reg < 4; reg++) {
            int row = rowBase + mt * 16 + quad * 4 + reg;
            if (row >= M) continue;
#pragma unroll
            for (int nt = 0; nt < 3; nt++) {
                int col = nt * 16 + r;
                U8[(size_t)row * 48 + col] = enc1(aU[mt][nt][reg]);
                if (col < DOUT) Out[(size_t)row * DOUT + col] = aO[mt][nt][reg] + bv[nt];
            }
        }
    }
}

// out0[dst,:] += inv_deg[dst] * mean-agg of U8 rows (fp8, stride 48).
__launch_bounds__(256)
__global__ void k_agg_add47_f8(const unsigned char* __restrict__ U8, const int* __restrict__ rowptr,
                               const int* __restrict__ colv, const float* __restrict__ invd,
                               float* __restrict__ out0, int N) {
    const int lane = threadIdx.x & 63;
    const int node = blockIdx.x * 4 + (threadIdx.x >> 6);
    if (node >= N) return;
    int beg = __builtin_amdgcn_readfirstlane(rowptr[node]);
    int end = __builtin_amdgcn_readfirstlane(rowptr[node + 1]);
    const int q = lane >> 4, sub = lane & 15;
    const bool act = sub < 12;
    const unsigned char* Us = U8 + sub * 4;

    float acc[4] = {0.f, 0.f, 0.f, 0.f};

    int j = beg;
    for (; j + 7 < end; j += 8) {
        int i0 = colv[j], i1 = colv[j + 1], i2 = colv[j + 2], i3 = colv[j + 3];
        int i4 = colv[j + 4], i5 = colv[j + 5], i6 = colv[j + 6], i7 = colv[j + 7];
        int sA = (q == 0) ? i0 : (q == 1) ? i1 : (q == 2) ? i2 : i3;
        int sB = (q == 0) ? i4 : (q == 1) ? i5 : (q == 2) ? i6 : i7;
        if (act) {
            unsigned a = *(const unsigned*)(Us + (size_t)sA * 48);
            unsigned b = *(const unsigned*)(Us + (size_t)sB * 48);
            addpk(a, acc); addpk(b, acc);
        }
    }
    if (j + 3 < end) {
        int i0 = colv[j], i1 = colv[j + 1], i2 = colv[j + 2], i3 = colv[j + 3];
        int sA = (q == 0) ? i0 : (q == 1) ? i1 : (q == 2) ? i2 : i3;
        if (act) {
            unsigned a = *(const unsigned*)(Us + (size_t)sA * 48);
            addpk(a, acc);
        }
        j += 4;
    }
    int rem = end - j;
    if (rem > 0) {
        int i0 = colv[j];
        int i1 = rem > 1 ? colv[j + 1] : i0;
        int i2 = rem > 2 ? colv[j + 2] : i0;
        int s = (q == 1) ? i1 : (q == 2) ? i2 : i0;
        if (act && q < rem) {
            unsigned a = *(const unsigned*)(Us + (size_t)s * 48);
            addpk(a, acc);
        }
    }

#pragma unroll
    for (int c = 0; c < 4; c++) {
        acc[c] += __shfl_xor(acc[c], 16);
        acc[c] += __shfl_xor(acc[c], 32);
    }

    if (q == 0 && act) {
        float sc = invd[node];
        int f0 = sub * 4;
        float* op = out0 + (size_t)node * DOUT;
#pragma unroll
        for (int c = 0; c < 4; c++)
            if (f0 + c < DOUT) op[f0 + c] += sc * acc[c];
    }
}

// ---------------------------------------------------------------------------
extern "C" void kernel_launch(void* const* d_in, const int* in_sizes, int n_in,
                              void* d_out, int out_size, void* d_ws, size_t ws_size,
                              hipStream_t stream) {
    const float* x   = (const float*)d_in[0];
    const int*   ei  = (const int*)d_in[1];
    const float* Wl0 = (const float*)d_in[2];
    const float* bl0 = (const float*)d_in[3];
    const float* Wr0 = (const float*)d_in[4];
    const float* Wl1 = (const float*)d_in[5];
    const float* bl1 = (const float*)d_in[6];
    const float* Wr1 = (const float*)d_in[7];
    const float* Wl2 = (const float*)d_in[8];
    const float* bl2 = (const float*)d_in[9];
    const float* Wr2 = (const float*)d_in[10];

    const int N = in_sizes[0] / DIN;
    const int E = in_sizes[1] / 2;
    const int nTiles = (N + 15) / 16;
    const size_t Mpad = (size_t)nTiles * 16 + 32;   // padded rows for fragment buffers

    char* p = (char*)d_ws;
    auto alloc = [&](size_t bytes) -> char* {
        char* r = p;
        p += (bytes + 255) & ~(size_t)255;
        return r;
    };
    int*   flag   = (int*)alloc(4);
    int*   cnt    = (int*)alloc((size_t)N * 4);
    int*   rowptr = (int*)alloc((size_t)(N + 1) * 4);
    int*   csum   = (int*)alloc(1024 * 4);
    int*   colbuf = (int*)alloc((size_t)E * 4 + 64);
    float* invd   = (float*)alloc((size_t)N * 4);
    int*   bucketCnt = (int*)alloc(1025 * 4);
    int*   bucketOff = (int*)alloc(1025 * 4);
    int*   bucketCur = (int*)alloc(1024 * 4);
    short* xbf    = (short*)alloc(Mpad * DIN * 2);   // x bf16 fragments; later reused as U8 [N,48] fp8
    short* bufA   = (short*)alloc(Mpad * DH * 2);    // agg output fragments; pre-agg: pairbuf
    short* h0     = (short*)alloc(Mpad * DH * 2);    // h0 bf16 fragments; hrelu in-place after L1
    unsigned*      x8 = (unsigned*)alloc((size_t)N * DIN);      // fp8 x (gather table, row-major)
    unsigned char* h8 = (unsigned char*)alloc((size_t)N * DH);  // fp8 relu(h0) (gather table, row-major)
    short* Pl0    = (short*)alloc((size_t)DIN * 256 * 2);
    short* Pr0    = (short*)alloc((size_t)DIN * 256 * 2);
    short* Pl1    = (short*)alloc((size_t)DH * 256 * 2);
    short* Pr1    = (short*)alloc((size_t)DH * 256 * 2);
    short* Pl2    = (short*)alloc((size_t)DH * 48 * 2);
    short* Pr2    = (short*)alloc((size_t)DH * 48 * 2);

    float* out0 = (float*)d_out;                        // [N,47]
    float* hout = (float*)d_out + (size_t)N * DOUT;     // [N,256] fp32 (output 1)

    // Bucketed CSR parameters: smallest span >= 128 with <= 1024 buckets.
    int span_shift = 7;
    while ((((N - 1) >> span_shift) + 1) > 1024 && span_shift < 21) span_shift++;
    const int NBK = ((N - 1) >> span_shift) + 1;
    const bool fast_csr = (NBK <= 1024) && ((1 << span_shift) <= 2048) &&
                          ((size_t)E * 8 <= Mpad * DH * 2);
    uint2* pairbuf = (uint2*)bufA;  // bufA dead until L0 agg

    hipMemsetAsync(flag, 0, 4, stream);
    hipMemsetAsync(cnt, 0, (size_t)N * 4, stream);
    hipMemsetAsync(bucketCnt, 0, (size_t)NBK * 4, stream);

    // --- CSR build ---
    const int nprobe = E < 4096 ? E : 4096;
    k_detect<<<(nprobe + 255) / 256, 256, 0, stream>>>(ei, flag, nprobe);
    if (fast_csr) {
        k_binhist<<<256, 256, 0, stream>>>(ei, flag, bucketCnt, E, span_shift, NBK);
        k_bucket_scan<<<1, 1024, 0, stream>>>(bucketCnt, bucketOff, bucketCur, NBK, E);
        k_binscatter<<<256, 256, 0, stream>>>(ei, flag, bucketOff, bucketCur, pairbuf, E, span_shift, NBK);
        k_bhist<<<NBK, 256, 0, stream>>>(pairbuf, bucketOff, cnt, span_shift, N);
    } else {
        k_hist<<<(E + 255) / 256, 256, 0, stream>>>(ei, flag, cnt, E);
    }
    const int nchunks = (N + 1023) / 1024;
    k_chunk_sum<<<nchunks, 256, 0, stream>>>(cnt, csum, N);
    k_scan_csum<<<1, 128, 0, stream>>>(csum, nchunks, rowptr, N, E);
    k_scan_apply<<<nchunks, 256, 0, stream>>>(cnt, csum, rowptr, N);
    hipMemsetAsync(cnt, 0, (size_t)N * 4, stream);
    if (fast_csr) {
        k_fill2<<<NBK, 256, 0, stream>>>(pairbuf, bucketOff, rowptr, cnt, colbuf, span_shift, N);
    } else {
        k_fill<<<(E + 255) / 256, 256, 0, stream>>>(ei, flag, rowptr, cnt, colbuf, E);
    }
    k_invdeg<<<(N + 255) / 256, 256, 0, stream>>>(rowptr, invd, N);

    // --- weight packing + x conversion ---
    k_pack<<<(4 * 16 * 64 + 255) / 256, 256, 0, stream>>>(Wl0, Pl0, 4, 16, 256);
    k_pack<<<(4 * 16 * 64 + 255) / 256, 256, 0, stream>>>(Wr0, Pr0, 4, 16, 256);
    k_pack<<<(8 * 16 * 64 + 255) / 256, 256, 0, stream>>>(Wl1, Pl1, 8, 16, 256);
    k_pack<<<(8 * 16 * 64 + 255) / 256, 256, 0, stream>>>(Wr1, Pr1, 8, 16, 256);
    k_pack<<<(8 * 3 * 64 + 255) / 256, 256, 0, stream>>>(Wl2, Pl2, 8, 3, DOUT);
    k_pack<<<(8 * 3 * 64 + 255) / 256, 256, 0, stream>>>(Wr2, Pr2, 8, 3, DOUT);
    k_f2bf8<<<nTiles, 256, 0, stream>>>(x, xbf, x8, nTiles, N);

    const int aggBlocks = (N + 3) / 4;
    const int gw = (N + 31) / 32;

    // Layer 0: h0 = bf16(relu(...)) fragments, h8 = fp8(relu(...)) row-major
    k_agg128_f8<<<aggBlocks, 256, 0, stream>>>((const unsigned char*)x8, rowptr, colbuf, invd, bufA, N);
    k_gemm_mfma_wide<<<gw, 256, 0, stream>>>(bufA, xbf, Pl0, Pr0, bl0,
                                             nullptr, h0, h8, N, DIN, DIN);

    // Layer 1: hout fp32 (output 1); hrelu bf16 fragments in-place over h0
    k_agg256_f8<<<aggBlocks, 256, 0, stream>>>(h8, rowptr, colbuf, invd, bufA, N);
    k_gemm_mfma_wide<<<gw, 256, 0, stream>>>(bufA, h0, Pl1, Pr1, bl1,
                                             hout, h0, nullptr, N, DH, DH);

    // Layer 2: U8 = fp8(hrelu@Wl2), out0 = hrelu@Wr2 + bl2; out0 += agg(U8)
    unsigned char* U8 = (unsigned char*)xbf;  // xbf dead after L0 GEMM
    k_gemm_mfma_out<<<(N + 127) / 128, 256, 0, stream>>>(h0, Pl2, Pr2, bl2, U8, out0, N);
    k_agg_add47_f8<<<aggBlocks, 256, 0, stream>>>(U8, rowptr, colbuf, invd, out0, N);
}

// Round 7
// 590.218 us; speedup vs baseline: 1.0888x; 1.0346x over previous
//
#include <hip/hip_runtime.h>
#include <cstdint>
#include <cstddef>

static constexpr int DIN  = 128;
static constexpr int DH   = 256;
static constexpr int DOUT = 47;

typedef __attribute__((ext_vector_type(8))) short bf16x8;
typedef __attribute__((ext_vector_type(4))) float f32x4;
typedef __attribute__((ext_vector_type(2))) float f32x2;

__device__ __forceinline__ short f2bf(float f) {
    unsigned u = __float_as_uint(f);
    unsigned r = (u + 0x7fffu + ((u >> 16) & 1u)) >> 16;  // RNE
    return (short)r;
}

// fp8 e4m3 (HW-native) helpers
__device__ __forceinline__ void addpk(unsigned w, float* a) {
    f32x2 lo = __builtin_amdgcn_cvt_pk_f32_fp8(w, false);
    f32x2 hi = __builtin_amdgcn_cvt_pk_f32_fp8(w, true);
    a[0] += lo[0]; a[1] += lo[1]; a[2] += hi[0]; a[3] += hi[1];
}
__device__ __forceinline__ unsigned enc4(float a, float b, float c, float d) {
    unsigned w = __builtin_amdgcn_cvt_pk_fp8_f32(a, b, 0, false);
    w = __builtin_amdgcn_cvt_pk_fp8_f32(c, d, w, true);
    return w;
}
__device__ __forceinline__ unsigned char enc1(float v) {
    return (unsigned char)(__builtin_amdgcn_cvt_pk_fp8_f32(v, v, 0, false) & 0xff);
}
__device__ __forceinline__ unsigned pbf2(float a, float b, float sc) {
    return (unsigned)(unsigned short)f2bf(a * sc) |
           ((unsigned)(unsigned short)f2bf(b * sc) << 16);
}

// A-fragment layout: value A[row][k] lives at
//   ((tile*nks + ks)*64 + q*16 + r)*8 + j   (shorts)
// with tile=row>>4, r=row&15, ks=k>>5, q=(k>>3)&3, j=k&7.
// A wave's load of one (tile,ks) fragment is 64 lanes x 16B contiguous.

// ---------------------------------------------------------------------------
// CSR build
__global__ void k_detect(const int* __restrict__ e, int* __restrict__ flag, int nprobe) {
    int i = blockIdx.x * blockDim.x + threadIdx.x;
    if (i < nprobe) {
        if (e[2 * i + 1] != 0) atomicOr(flag, 1);
    }
}

// Legacy fallback path (used only when bucket params don't fit)
__global__ void k_hist(const int* __restrict__ e, const int* __restrict__ flag,
                       int* __restrict__ cnt, int E) {
    int i = blockIdx.x * blockDim.x + threadIdx.x;
    if (i >= E) return;
    int is32 = *flag;
    int d = is32 ? e[E + i] : e[2 * (E + i)];
    atomicAdd(&cnt[d], 1);
}

__global__ void k_fill(const int* __restrict__ e, const int* __restrict__ flag,
                       const int* __restrict__ rowptr, int* __restrict__ cursor,
                       int* __restrict__ colbuf, int E) {
    int i = blockIdx.x * blockDim.x + threadIdx.x;
    if (i >= E) return;
    int is32 = *flag;
    int s = is32 ? e[i] : e[2 * i];
    int d = is32 ? e[E + i] : e[2 * (E + i)];
    int pos = atomicAdd(&cursor[d], 1);
    colbuf[rowptr[d] + pos] = s;
}

// --- Fast bucketed CSR build ------------------------------------------------
__launch_bounds__(256)
__global__ void k_binhist(const int* __restrict__ e, const int* __restrict__ flag,
                          int* __restrict__ bucketCnt, int E, int shift, int nbk) {
    __shared__ int h[1024];
    int t = threadIdx.x;
    for (int i = t; i < nbk; i += 256) h[i] = 0;
    __syncthreads();
    int is32 = *flag;
    int stride = gridDim.x * 256;
    for (int i = blockIdx.x * 256 + t; i < E; i += stride) {
        int d = is32 ? e[E + i] : e[2 * (E + i)];
        atomicAdd(&h[d >> shift], 1);
    }
    __syncthreads();
    for (int i = t; i < nbk; i += 256) {
        int v = h[i];
        if (v) atomicAdd(&bucketCnt[i], v);
    }
}

__global__ void k_bucket_scan(const int* __restrict__ bucketCnt, int* __restrict__ bucketOff,
                              int* __restrict__ bucketCur, int nbk, int E) {
    __shared__ int s[1024];
    int t = threadIdx.x;
    int v = (t < nbk) ? bucketCnt[t] : 0;
    s[t] = v;
    __syncthreads();
    for (int off = 1; off < 1024; off <<= 1) {
        int xv = (t >= off) ? s[t - off] : 0;
        __syncthreads();
        s[t] += xv;
        __syncthreads();
    }
    if (t < nbk) { bucketOff[t] = s[t] - v; bucketCur[t] = 0; }
    if (t == 0) bucketOff[nbk] = E;
}

__launch_bounds__(256)
__global__ void k_binscatter(const int* __restrict__ e, const int* __restrict__ flag,
                             const int* __restrict__ bucketOff, int* __restrict__ bucketCur,
                             uint2* __restrict__ pairbuf, int E, int shift, int nbk) {
    __shared__ int h[1024];
    __shared__ int cur[1024];
    int t = threadIdx.x;
    for (int i = t; i < nbk; i += 256) h[i] = 0;
    __syncthreads();
    int is32 = *flag;
    int chunk = (E + gridDim.x - 1) / gridDim.x;
    int lo = blockIdx.x * chunk;
    int hi = lo + chunk < E ? lo + chunk : E;
    for (int i = lo + t; i < hi; i += 256) {
        int d = is32 ? e[E + i] : e[2 * (E + i)];
        atomicAdd(&h[d >> shift], 1);
    }
    __syncthreads();
    for (int i = t; i < nbk; i += 256) {
        int c = h[i];
        int base = c ? atomicAdd(&bucketCur[i], c) : 0;
        h[i] = bucketOff[i] + base;
        cur[i] = 0;
    }
    __syncthreads();
    for (int i = lo + t; i < hi; i += 256) {
        int sv = is32 ? e[i] : e[2 * i];
        int d  = is32 ? e[E + i] : e[2 * (E + i)];
        int b = d >> shift;
        int lp = atomicAdd(&cur[b], 1);
        pairbuf[h[b] + lp] = make_uint2((unsigned)sv, (unsigned)d);
    }
}

__launch_bounds__(256)
__global__ void k_bhist(const uint2* __restrict__ pairbuf, const int* __restrict__ bucketOff,
                        int* __restrict__ cnt, int shift, int N) {
    __shared__ int h[2048];
    int b = blockIdx.x;
    int t = threadIdx.x;
    int first = b << shift;
    int span = (1 << shift);
    if (first + span > N) span = N - first;
    for (int i = t; i < span; i += 256) h[i] = 0;
    __syncthreads();
    int lo = bucketOff[b], hi = bucketOff[b + 1];
    for (int j = lo + t; j < hi; j += 256) {
        int d = (int)pairbuf[j].y;
        atomicAdd(&h[d - first], 1);
    }
    __syncthreads();
    for (int i = t; i < span; i += 256) cnt[first + i] = h[i];
}

#define FILL_CAP 12288
__launch_bounds__(256)
__global__ void k_fill2(const uint2* __restrict__ pairbuf, const int* __restrict__ bucketOff,
                        const int* __restrict__ rowptr, int* __restrict__ cursor,
                        int* __restrict__ colbuf, int shift, int N) {
    __shared__ int cur[2048];
    __shared__ int sbuf[FILL_CAP];
    int b = blockIdx.x;
    int t = threadIdx.x;
    int first = b << shift;
    int span = (1 << shift);
    if (first + span > N) span = N - first;
    int lo = bucketOff[b], hi = bucketOff[b + 1];
    int nEdge = hi - lo;
    int base = rowptr[first];
    if (nEdge <= FILL_CAP) {
        for (int i = t; i < span; i += 256) cur[i] = rowptr[first + i] - base;
        __syncthreads();
        for (int j = lo + t; j < hi; j += 256) {
            uint2 p = pairbuf[j];
            int lp = atomicAdd(&cur[(int)p.y - first], 1);
            sbuf[lp] = (int)p.x;
        }
        __syncthreads();
        for (int i = t; i < nEdge; i += 256) colbuf[base + i] = sbuf[i];
    } else {
        for (int j = lo + t; j < hi; j += 256) {
            uint2 p = pairbuf[j];
            int d = (int)p.y;
            int pos = atomicAdd(&cursor[d], 1);
            colbuf[rowptr[d] + pos] = (int)p.x;
        }
    }
}

__global__ void k_chunk_sum(const int* __restrict__ cnt, int* __restrict__ csum, int n) {
    int base = blockIdx.x * 1024;
    int t = threadIdx.x;
    int s = 0;
#pragma unroll
    for (int j = 0; j < 4; j++) {
        int i = base + t * 4 + j;
        if (i < n) s += cnt[i];
    }
    __shared__ int red[256];
    red[t] = s;
    __syncthreads();
    for (int off = 128; off > 0; off >>= 1) {
        if (t < off) red[t] += red[t + off];
        __syncthreads();
    }
    if (t == 0) csum[blockIdx.x] = red[0];
}

__global__ void k_scan_csum(int* __restrict__ csum, int n,
                            int* __restrict__ rowptr, int N, int E) {
    __shared__ int s[128];
    int t = threadIdx.x;
    int v = (t < n) ? csum[t] : 0;
    s[t] = v;
    __syncthreads();
    for (int off = 1; off < 128; off <<= 1) {
        int xv = (t >= off) ? s[t - off] : 0;
        __syncthreads();
        s[t] += xv;
        __syncthreads();
    }
    if (t < n) csum[t] = s[t] - v;  // exclusive
    if (t == 0) rowptr[N] = E;
}

__global__ void k_scan_apply(const int* __restrict__ cnt, const int* __restrict__ csum,
                             int* __restrict__ rowptr, int n) {
    int base = blockIdx.x * 1024, t = threadIdx.x;
    int i0 = base + t * 4;
    int v[4];
#pragma unroll
    for (int j = 0; j < 4; j++) {
        int i = i0 + j;
        v[j] = (i < n) ? cnt[i] : 0;
    }
    int tsum = v[0] + v[1] + v[2] + v[3];
    __shared__ int s[256];
    s[t] = tsum;
    __syncthreads();
    for (int off = 1; off < 256; off <<= 1) {
        int xv = (t >= off) ? s[t - off] : 0;
        __syncthreads();
        s[t] += xv;
        __syncthreads();
    }
    int excl = s[t] - tsum + csum[blockIdx.x];
#pragma unroll
    for (int j = 0; j < 4; j++) {
        int i = i0 + j;
        if (i < n) rowptr[i] = excl;
        excl += v[j];
    }
}

__global__ void k_invdeg(const int* __restrict__ rowptr, float* __restrict__ invd, int N) {
    int i = blockIdx.x * blockDim.x + threadIdx.x;
    if (i >= N) return;
    int d = rowptr[i + 1] - rowptr[i];
    invd[i] = 1.0f / (float)(d > 1 ? d : 1);
}

// ---------------------------------------------------------------------------
// fp32 x -> bf16 A-fragments (GEMM A2, nks=4) + fp8 row-major (gather table).
__global__ void k_f2bf8(const float* __restrict__ X, short* __restrict__ Yb,
                        unsigned* __restrict__ Y8, int nTiles, int N) {
    int t = blockIdx.x * 256 + threadIdx.x;
    int total = nTiles * 4 * 64;
    if (t >= total) return;
    int lane = t & 63;
    int kt = t >> 6;          // tile*4 + ks
    int ks = kt & 3;
    int tile = kt >> 2;
    int q = (lane >> 4) & 3;
    int r = lane & 15;
    int row = tile * 16 + r;
    int col = ks * 32 + q * 8;
    bf16x8 o = (bf16x8)(short)0;
    if (row < N) {
        const float* src = X + (size_t)row * DIN + col;
        float4 v0 = *(const float4*)src;
        float4 v1 = *(const float4*)(src + 4);
        o[0] = f2bf(v0.x); o[1] = f2bf(v0.y); o[2] = f2bf(v0.z); o[3] = f2bf(v0.w);
        o[4] = f2bf(v1.x); o[5] = f2bf(v1.y); o[6] = f2bf(v1.z); o[7] = f2bf(v1.w);
        unsigned* p8 = Y8 + ((size_t)row * DIN + col) / 4;
        p8[0] = enc4(v0.x, v0.y, v0.z, v0.w);
        p8[1] = enc4(v1.x, v1.y, v1.z, v1.w);
    }
    *(bf16x8*)(Yb + (size_t)t * 8) = o;
}

// Pack fp32 weight [K, Ncols] into bf16 B-fragment order for mfma_16x16x32
__global__ void k_pack(const float* __restrict__ W, short* __restrict__ P,
                       int ksteps, int Nt, int Ncols) {
    int idx = blockIdx.x * 256 + threadIdx.x;
    int total = ksteps * Nt * 64;
    if (idx >= total) return;
    int lane = idx & 63;
    int t = idx >> 6;
    int nt = t % Nt;
    int ks = t / Nt;
    int n = nt * 16 + (lane & 15);
    int kb = ks * 32 + (lane >> 4) * 8;
    bf16x8 o;
#pragma unroll
    for (int j = 0; j < 8; j++)
        o[j] = (n < Ncols) ? f2bf(W[(size_t)(kb + j) * Ncols + n]) : (short)0;
    *(bf16x8*)(P + (size_t)idx * 8) = o;
}

// ---------------------------------------------------------------------------
// 256-wide fp8 CSR mean-agg. Output: bf16 A-fragments (nks=8).
__launch_bounds__(256)
__global__ void k_agg256_f8(const unsigned char* __restrict__ X8, const int* __restrict__ rowptr,
                            const int* __restrict__ colv, const float* __restrict__ invd,
                            short* __restrict__ out, int N) {
    const int lane = threadIdx.x & 63;
    const int node = blockIdx.x * 4 + (threadIdx.x >> 6);
    if (node >= N) return;
    int beg = __builtin_amdgcn_readfirstlane(rowptr[node]);
    int end = __builtin_amdgcn_readfirstlane(rowptr[node + 1]);
    const int q = lane >> 4, sub = lane & 15;
    const unsigned char* Xs = X8 + sub * 16;

    float acc[16];
#pragma unroll
    for (int c = 0; c < 16; c++) acc[c] = 0.f;

    auto addv = [&](uint4 a) {
        addpk(a.x, acc); addpk(a.y, acc + 4); addpk(a.z, acc + 8); addpk(a.w, acc + 12);
    };

    int j = beg;
    for (; j + 7 < end; j += 8) {
        int i0 = colv[j], i1 = colv[j + 1], i2 = colv[j + 2], i3 = colv[j + 3];
        int i4 = colv[j + 4], i5 = colv[j + 5], i6 = colv[j + 6], i7 = colv[j + 7];
        int sA = (q == 0) ? i0 : (q == 1) ? i1 : (q == 2) ? i2 : i3;
        int sB = (q == 0) ? i4 : (q == 1) ? i5 : (q == 2) ? i6 : i7;
        uint4 a = *(const uint4*)(Xs + (size_t)sA * 256);
        uint4 b = *(const uint4*)(Xs + (size_t)sB * 256);
        addv(a); addv(b);
    }
    if (j + 3 < end) {
        int i0 = colv[j], i1 = colv[j + 1], i2 = colv[j + 2], i3 = colv[j + 3];
        int sA = (q == 0) ? i0 : (q == 1) ? i1 : (q == 2) ? i2 : i3;
        uint4 a = *(const uint4*)(Xs + (size_t)sA * 256);
        addv(a);
        j += 4;
    }
    int rem = end - j;
    if (rem > 0) {
        int i0 = colv[j];
        int i1 = rem > 1 ? colv[j + 1] : i0;
        int i2 = rem > 2 ? colv[j + 2] : i0;
        int s = (q == 1) ? i1 : (q == 2) ? i2 : i0;
        uint4 a = *(const uint4*)(Xs + (size_t)s * 256);
        if (q < rem) addv(a);
    }

#pragma unroll
    for (int c = 0; c < 16; c++) {
        acc[c] += __shfl_xor(acc[c], 16);
        acc[c] += __shfl_xor(acc[c], 32);
    }

    if (q == 0) {
        float sc = invd[node];
        uint4 o0, o1;
        o0.x = pbf2(acc[0], acc[1], sc);   o0.y = pbf2(acc[2], acc[3], sc);
        o0.z = pbf2(acc[4], acc[5], sc);   o0.w = pbf2(acc[6], acc[7], sc);
        o1.x = pbf2(acc[8], acc[9], sc);   o1.y = pbf2(acc[10], acc[11], sc);
        o1.z = pbf2(acc[12], acc[13], sc); o1.w = pbf2(acc[14], acc[15], sc);
        const int tile = node >> 4, r = node & 15;
        const int ksC = sub >> 1, q1 = (sub & 1) * 2;
        size_t base = ((size_t)(tile * 8 + ksC) * 64 + r) * 8;
        *(uint4*)(out + base + (size_t)q1 * 128)       = o0;
        *(uint4*)(out + base + (size_t)(q1 + 1) * 128) = o1;
    }
}

// 128-wide fp8 CSR mean-agg. Output: bf16 A-fragments (nks=4).
__launch_bounds__(256)
__global__ void k_agg128_f8(const unsigned char* __restrict__ X8, const int* __restrict__ rowptr,
                            const int* __restrict__ colv, const float* __restrict__ invd,
                            short* __restrict__ out, int N) {
    const int lane = threadIdx.x & 63;
    const int node = blockIdx.x * 4 + (threadIdx.x >> 6);
    if (node >= N) return;
    int beg = __builtin_amdgcn_readfirstlane(rowptr[node]);
    int end = __builtin_amdgcn_readfirstlane(rowptr[node + 1]);
    const int grp = lane >> 3, sub = lane & 7;
    const unsigned char* Xs = X8 + sub * 16;

    float acc[16];
#pragma unroll
    for (int c = 0; c < 16; c++) acc[c] = 0.f;

    auto addv = [&](uint4 a) {
        addpk(a.x, acc); addpk(a.y, acc + 4); addpk(a.z, acc + 8); addpk(a.w, acc + 12);
    };

    int j = beg;
    for (; j + 15 < end; j += 16) {
        int sA = colv[j + grp];
        int sB = colv[j + 8 + grp];
        uint4 a = *(const uint4*)(Xs + (size_t)sA * 128);
        uint4 b = *(const uint4*)(Xs + (size_t)sB * 128);
        addv(a); addv(b);
    }
    if (j + 7 < end) {
        int sA = colv[j + grp];
        uint4 a = *(const uint4*)(Xs + (size_t)sA * 128);
        addv(a);
        j += 8;
    }
    int rem = end - j;
    if (rem > 0) {
        int sA = colv[j + (grp < rem ? grp : 0)];
        uint4 a = *(const uint4*)(Xs + (size_t)sA * 128);
        if (grp < rem) addv(a);
    }

#pragma unroll
    for (int c = 0; c < 16; c++) {
        acc[c] += __shfl_xor(acc[c], 8);
        acc[c] += __shfl_xor(acc[c], 16);
        acc[c] += __shfl_xor(acc[c], 32);
    }

    if (grp == 0) {
        float sc = invd[node];
        uint4 o0, o1;
        o0.x = pbf2(acc[0], acc[1], sc);   o0.y = pbf2(acc[2], acc[3], sc);
        o0.z = pbf2(acc[4], acc[5], sc);   o0.w = pbf2(acc[6], acc[7], sc);
        o1.x = pbf2(acc[8], acc[9], sc);   o1.y = pbf2(acc[10], acc[11], sc);
        o1.z = pbf2(acc[12], acc[13], sc); o1.w = pbf2(acc[14], acc[15], sc);
        const int tile = node >> 4, r = node & 15;
        const int ksC = sub >> 1, q1 = (sub & 1) * 2;
        size_t base = ((size_t)(tile * 4 + ksC) * 64 + r) * 8;
        *(uint4*)(out + base + (size_t)q1 * 128)       = o0;
        *(uint4*)(out + base + (size_t)(q1 + 1) * 128) = o1;
    }
}

// ---------------------------------------------------------------------------
// LDS-free dual-A bf16 MFMA GEMM; A in fragment order, dist-1 prefetch,
// acc[2][4], 32-row blocks. Cb (fragment order, nks=8) and C8 (row-major)
// are staged in LDS and written out as dense full-line copies (the direct
// per-short/per-byte stores cost ~26MB of partial-line RMW amplification).
__launch_bounds__(256, 4)
__global__ void k_gemm_mfma_wide(const short* __restrict__ A1, const short* A2,
                                 const short* __restrict__ P1, const short* __restrict__ P2,
                                 const float* __restrict__ bias,
                                 float* Cf, short* Cb, unsigned char* C8,
                                 int M, int K1, int K2) {
    __shared__ short sCb[8192];            // 2 tiles x 8 ks x 64 lanes x 8 shorts
    __shared__ unsigned char sC8[8192];    // 32 rows x 256 cols
    const int lane = threadIdx.x & 63;
    const int wave = threadIdx.x >> 6;
    const int quad = lane >> 4;
    const int r    = lane & 15;
    const int rowBase = blockIdx.x * 32;
    const int tile0 = blockIdx.x * 2;

    f32x4 acc[2][4];
#pragma unroll
    for (int mt = 0; mt < 2; mt++)
#pragma unroll
        for (int nt = 0; nt < 4; nt++) acc[mt][nt] = (f32x4)(0.f);

    for (int src = 0; src < 2; src++) {
        const short* A = src ? A2 : A1;
        const short* P = src ? P2 : P1;
        const int K = src ? K2 : K1;
        const int nks = K >> 5;

        bf16x8 af[2], bfr[4];
#pragma unroll
        for (int mt = 0; mt < 2; mt++)
            af[mt] = *(const bf16x8*)(A + (((size_t)(tile0 + mt) * nks * 64 + lane) << 3));
#pragma unroll
        for (int nt = 0; nt < 4; nt++)
            bfr[nt] = *(const bf16x8*)(P + (((size_t)(wave * 4 + nt) * 64 + lane) << 3));

        for (int ks = 0; ks < nks; ks++) {
            const int ksn = (ks + 1 < nks) ? ks + 1 : ks;
            bf16x8 afn[2], bfn[4];
#pragma unroll
            for (int mt = 0; mt < 2; mt++)
                afn[mt] = *(const bf16x8*)(A + ((((size_t)(tile0 + mt) * nks + ksn) * 64 + lane) << 3));
#pragma unroll
            for (int nt = 0; nt < 4; nt++)
                bfn[nt] = *(const bf16x8*)(P + (((size_t)(ksn * 16 + wave * 4 + nt) * 64 + lane) << 3));
#pragma unroll
            for (int mt = 0; mt < 2; mt++)
#pragma unroll
                for (int nt = 0; nt < 4; nt++)
                    acc[mt][nt] = __builtin_amdgcn_mfma_f32_16x16x32_bf16(
                        af[mt], bfr[nt], acc[mt][nt], 0, 0, 0);
#pragma unroll
            for (int mt = 0; mt < 2; mt++) af[mt] = afn[mt];
#pragma unroll
            for (int nt = 0; nt < 4; nt++) bfr[nt] = bfn[nt];
        }
    }

    __syncthreads();  // guard in-place Cb == A2 (block touches only its own tiles)

    float bv[4];
#pragma unroll
    for (int nt = 0; nt < 4; nt++) bv[nt] = bias[wave * 64 + nt * 16 + r];

#pragma unroll
    for (int mt = 0; mt < 2; mt++) {
#pragma unroll
        for (int reg = 0; reg < 4; reg++) {
            int rC = quad * 4 + reg;
            int row = rowBase + mt * 16 + rC;
#pragma unroll
            for (int nt = 0; nt < 4; nt++) {
                int col = wave * 64 + nt * 16 + r;
                float v = acc[mt][nt][reg] + bv[nt];
                if (Cf && row < M) Cf[(size_t)row * 256 + col] = v;
                if (Cb) {
                    int ksC = wave * 2 + (nt >> 1);
                    int qC  = (nt & 1) * 2 + (r >> 3);
                    sCb[(((mt * 8 + ksC) * 64 + qC * 16 + rC) << 3) + (r & 7)] = f2bf(fmaxf(v, 0.f));
                }
                if (C8) sC8[(mt * 16 + rC) * 256 + col] = enc1(fmaxf(v, 0.f));
            }
        }
    }

    __syncthreads();
    if (Cb) {
        uint4* d = (uint4*)(Cb + ((size_t)tile0 << 12));
        const uint4* s = (const uint4*)sCb;
        for (int i = threadIdx.x; i < 1024; i += 256) d[i] = s[i];
    }
    if (C8) {
        uint4* d = (uint4*)(C8 + ((size_t)rowBase << 8));
        const uint4* s = (const uint4*)sC8;
        for (int i = threadIdx.x; i < 512; i += 256) d[i] = s[i];
    }
}

// Layer-2 fused dual-W MFMA: U (fp8, stride 48, LDS-staged dense write) +
// Out (fp32, [M,47], direct). A in fragment order (nks=8), dist-1 prefetch.
__launch_bounds__(256, 4)
__global__ void k_gemm_mfma_out(const short* __restrict__ A,
                                const short* __restrict__ Pl, const short* __restrict__ Pr,
                                const float* __restrict__ bias,
                                unsigned char* __restrict__ U8, float* __restrict__ Out, int M) {
    __shared__ unsigned char sU8[6144];    // 128 rows x 48B
    const int lane = threadIdx.x & 63;
    const int wave = threadIdx.x >> 6;
    const int quad = lane >> 4;
    const int r    = lane & 15;
    const int rowBase = blockIdx.x * 128 + wave * 32;
    const int tile0 = blockIdx.x * 8 + wave * 2;

    f32x4 aU[2][3], aO[2][3];
#pragma unroll
    for (int mt = 0; mt < 2; mt++)
#pragma unroll
        for (int nt = 0; nt < 3; nt++) { aU[mt][nt] = (f32x4)(0.f); aO[mt][nt] = (f32x4)(0.f); }

    bf16x8 af[2];
#pragma unroll
    for (int mt = 0; mt < 2; mt++)
        af[mt] = *(const bf16x8*)(A + (((size_t)(tile0 + mt) * 8 * 64 + lane) << 3));

    for (int ks = 0; ks < 8; ks++) {
        const int ksn = (ks + 1 < 8) ? ks + 1 : ks;
        bf16x8 afn[2], bl[3], br[3];
#pragma unroll
        for (int mt = 0; mt < 2; mt++)
            afn[mt] = *(const bf16x8*)(A + ((((size_t)(tile0 + mt) * 8 + ksn) * 64 + lane) << 3));
#pragma unroll
        for (int nt = 0; nt < 3; nt++) {
            size_t fo = (((size_t)(ks * 3 + nt) * 64 + lane) << 3);
            bl[nt] = *(const bf16x8*)(Pl + fo);
            br[nt] = *(const bf16x8*)(Pr + fo);
        }
#pragma unroll
        for (int mt = 0; mt < 2; mt++)
#pragma unroll
            for (int nt = 0; nt < 3; nt++) {
                aU[mt][nt] = __builtin_amdgcn_mfma_f32_16x16x32_bf16(af[mt], bl[nt], aU[mt][nt], 0, 0, 0);
                aO[mt][nt] = __builtin_amdgcn_mfma_f32_16x16x32_bf16(af[mt], br[nt], aO[mt][nt], 0, 0, 0);
            }
#pragma unroll
        for (int mt = 0; mt < 2; mt++) af[mt] = afn[mt];
    }

    float bv[3];
#pragma unroll
    for (int nt = 0; nt < 3; nt++) {
        int col = nt * 16 + r;
        bv[nt] = (col < DOUT) ? bias[col] : 0.f;
    }

#pragma unroll
    for (int mt = 0; mt < 2; mt++) {
#pragma unroll
        for (int reg = 0; reg < 4; reg++) {
            int rloc = wave * 32 + mt * 16 + quad * 4 + reg;
            int row = blockIdx.x * 128 + rloc;
#pragma unroll
            for (int nt = 0; nt < 3; nt++) {
                int col = nt * 16 + r;
                sU8[rloc * 48 + col] = enc1(aU[mt][nt][reg]);
                if (row < M && col < DOUT) Out[(size_t)row * DOUT + col] = aO[mt][nt][reg] + bv[nt];
            }
        }
    }

    __syncthreads();
    {
        uint4* d = (uint4*)(U8 + (size_t)blockIdx.x * 6144);
        const uint4* s = (const uint4*)sU8;
        for (int i = threadIdx.x; i < 384; i += 256) d[i] = s[i];
    }
}

// out0[dst,:] += inv_deg[dst] * mean-agg of U8 rows (fp8, stride 48).
__launch_bounds__(256)
__global__ void k_agg_add47_f8(const unsigned char* __restrict__ U8, const int* __restrict__ rowptr,
                               const int* __restrict__ colv, const float* __restrict__ invd,
                               float* __restrict__ out0, int N) {
    const int lane = threadIdx.x & 63;
    const int node = blockIdx.x * 4 + (threadIdx.x >> 6);
    if (node >= N) return;
    int beg = __builtin_amdgcn_readfirstlane(rowptr[node]);
    int end = __builtin_amdgcn_readfirstlane(rowptr[node + 1]);
    const int q = lane >> 4, sub = lane & 15;
    const bool act = sub < 12;
    const unsigned char* Us = U8 + sub * 4;

    float acc[4] = {0.f, 0.f, 0.f, 0.f};

    int j = beg;
    for (; j + 7 < end; j += 8) {
        int i0 = colv[j], i1 = colv[j + 1], i2 = colv[j + 2], i3 = colv[j + 3];
        int i4 = colv[j + 4], i5 = colv[j + 5], i6 = colv[j + 6], i7 = colv[j + 7];
        int sA = (q == 0) ? i0 : (q == 1) ? i1 : (q == 2) ? i2 : i3;
        int sB = (q == 0) ? i4 : (q == 1) ? i5 : (q == 2) ? i6 : i7;
        if (act) {
            unsigned a = *(const unsigned*)(Us + (size_t)sA * 48);
            unsigned b = *(const unsigned*)(Us + (size_t)sB * 48);
            addpk(a, acc); addpk(b, acc);
        }
    }
    if (j + 3 < end) {
        int i0 = colv[j], i1 = colv[j + 1], i2 = colv[j + 2], i3 = colv[j + 3];
        int sA = (q == 0) ? i0 : (q == 1) ? i1 : (q == 2) ? i2 : i3;
        if (act) {
            unsigned a = *(const unsigned*)(Us + (size_t)sA * 48);
            addpk(a, acc);
        }
        j += 4;
    }
    int rem = end - j;
    if (rem > 0) {
        int i0 = colv[j];
        int i1 = rem > 1 ? colv[j + 1] : i0;
        int i2 = rem > 2 ? colv[j + 2] : i0;
        int s = (q == 1) ? i1 : (q == 2) ? i2 : i0;
        if (act && q < rem) {
            unsigned a = *(const unsigned*)(Us + (size_t)s * 48);
            addpk(a, acc);
        }
    }

#pragma unroll
    for (int c = 0; c < 4; c++) {
        acc[c] += __shfl_xor(acc[c], 16);
        acc[c] += __shfl_xor(acc[c], 32);
    }

    if (q == 0 && act) {
        float sc = invd[node];
        int f0 = sub * 4;
        float* op = out0 + (size_t)node * DOUT;
#pragma unroll
        for (int c = 0; c < 4; c++)
            if (f0 + c < DOUT) op[f0 + c] += sc * acc[c];
    }
}

// ---------------------------------------------------------------------------
extern "C" void kernel_launch(void* const* d_in, const int* in_sizes, int n_in,
                              void* d_out, int out_size, void* d_ws, size_t ws_size,
                              hipStream_t stream) {
    const float* x   = (const float*)d_in[0];
    const int*   ei  = (const int*)d_in[1];
    const float* Wl0 = (const float*)d_in[2];
    const float* bl0 = (const float*)d_in[3];
    const float* Wr0 = (const float*)d_in[4];
    const float* Wl1 = (const float*)d_in[5];
    const float* bl1 = (const float*)d_in[6];
    const float* Wr1 = (const float*)d_in[7];
    const float* Wl2 = (const float*)d_in[8];
    const float* bl2 = (const float*)d_in[9];
    const float* Wr2 = (const float*)d_in[10];

    const int N = in_sizes[0] / DIN;
    const int E = in_sizes[1] / 2;
    const int nTiles = (N + 15) / 16;
    const size_t Mpad = (size_t)nTiles * 16 + 128;   // padded rows for fragment buffers

    char* p = (char*)d_ws;
    auto alloc = [&](size_t bytes) -> char* {
        char* r = p;
        p += (bytes + 255) & ~(size_t)255;
        return r;
    };
    int*   flag   = (int*)alloc(4);
    int*   cnt    = (int*)alloc((size_t)N * 4);
    int*   rowptr = (int*)alloc((size_t)(N + 1) * 4);
    int*   csum   = (int*)alloc(1024 * 4);
    int*   colbuf = (int*)alloc((size_t)E * 4 + 64);
    float* invd   = (float*)alloc((size_t)N * 4);
    int*   bucketCnt = (int*)alloc(1025 * 4);
    int*   bucketOff = (int*)alloc(1025 * 4);
    int*   bucketCur = (int*)alloc(1024 * 4);
    short* xbf    = (short*)alloc(Mpad * DIN * 2);   // x bf16 fragments; later reused as U8 [*,48] fp8
    short* bufA   = (short*)alloc(Mpad * DH * 2);    // agg output fragments; pre-agg: pairbuf
    short* h0     = (short*)alloc(Mpad * DH * 2);    // h0 bf16 fragments; hrelu in-place after L1
    unsigned*      x8 = (unsigned*)alloc((size_t)N * DIN);  // fp8 x (gather table, row-major)
    unsigned char* h8 = (unsigned char*)alloc(Mpad * DH);   // fp8 relu(h0) (gather table, padded)
    short* Pl0    = (short*)alloc((size_t)DIN * 256 * 2);
    short* Pr0    = (short*)alloc((size_t)DIN * 256 * 2);
    short* Pl1    = (short*)alloc((size_t)DH * 256 * 2);
    short* Pr1    = (short*)alloc((size_t)DH * 256 * 2);
    short* Pl2    = (short*)alloc((size_t)DH * 48 * 2);
    short* Pr2    = (short*)alloc((size_t)DH * 48 * 2);

    float* out0 = (float*)d_out;                        // [N,47]
    float* hout = (float*)d_out + (size_t)N * DOUT;     // [N,256] fp32 (output 1)

    // Bucketed CSR parameters: smallest span >= 128 with <= 1024 buckets.
    int span_shift = 7;
    while ((((N - 1) >> span_shift) + 1) > 1024 && span_shift < 21) span_shift++;
    const int NBK = ((N - 1) >> span_shift) + 1;
    const bool fast_csr = (NBK <= 1024) && ((1 << span_shift) <= 2048) &&
                          ((size_t)E * 8 <= Mpad * DH * 2);
    uint2* pairbuf = (uint2*)bufA;  // bufA dead until L0 agg

    hipMemsetAsync(flag, 0, 4, stream);
    hipMemsetAsync(cnt, 0, (size_t)N * 4, stream);
    hipMemsetAsync(bucketCnt, 0, (size_t)NBK * 4, stream);

    // --- CSR build ---
    const int nprobe = E < 4096 ? E : 4096;
    k_detect<<<(nprobe + 255) / 256, 256, 0, stream>>>(ei, flag, nprobe);
    if (fast_csr) {
        k_binhist<<<256, 256, 0, stream>>>(ei, flag, bucketCnt, E, span_shift, NBK);
        k_bucket_scan<<<1, 1024, 0, stream>>>(bucketCnt, bucketOff, bucketCur, NBK, E);
        k_binscatter<<<256, 256, 0, stream>>>(ei, flag, bucketOff, bucketCur, pairbuf, E, span_shift, NBK);
        k_bhist<<<NBK, 256, 0, stream>>>(pairbuf, bucketOff, cnt, span_shift, N);
    } else {
        k_hist<<<(E + 255) / 256, 256, 0, stream>>>(ei, flag, cnt, E);
    }
    const int nchunks = (N + 1023) / 1024;
    k_chunk_sum<<<nchunks, 256, 0, stream>>>(cnt, csum, N);
    k_scan_csum<<<1, 128, 0, stream>>>(csum, nchunks, rowptr, N, E);
    k_scan_apply<<<nchunks, 256, 0, stream>>>(cnt, csum, rowptr, N);
    hipMemsetAsync(cnt, 0, (size_t)N * 4, stream);
    if (fast_csr) {
        k_fill2<<<NBK, 256, 0, stream>>>(pairbuf, bucketOff, rowptr, cnt, colbuf, span_shift, N);
    } else {
        k_fill<<<(E + 255) / 256, 256, 0, stream>>>(ei, flag, rowptr, cnt, colbuf, E);
    }
    k_invdeg<<<(N + 255) / 256, 256, 0, stream>>>(rowptr, invd, N);

    // --- weight packing + x conversion ---
    k_pack<<<(4 * 16 * 64 + 255) / 256, 256, 0, stream>>>(Wl0, Pl0, 4, 16, 256);
    k_pack<<<(4 * 16 * 64 + 255) / 256, 256, 0, stream>>>(Wr0, Pr0, 4, 16, 256);
    k_pack<<<(8 * 16 * 64 + 255) / 256, 256, 0, stream>>>(Wl1, Pl1, 8, 16, 256);
    k_pack<<<(8 * 16 * 64 + 255) / 256, 256, 0, stream>>>(Wr1, Pr1, 8, 16, 256);
    k_pack<<<(8 * 3 * 64 + 255) / 256, 256, 0, stream>>>(Wl2, Pl2, 8, 3, DOUT);
    k_pack<<<(8 * 3 * 64 + 255) / 256, 256, 0, stream>>>(Wr2, Pr2, 8, 3, DOUT);
    k_f2bf8<<<nTiles, 256, 0, stream>>>(x, xbf, x8, nTiles, N);

    const int aggBlocks = (N + 3) / 4;
    const int gw = (N + 31) / 32;

    // Layer 0: h0 = bf16(relu(...)) fragments, h8 = fp8(relu(...)) row-major
    k_agg128_f8<<<aggBlocks, 256, 0, stream>>>((const unsigned char*)x8, rowptr, colbuf, invd, bufA, N);
    k_gemm_mfma_wide<<<gw, 256, 0, stream>>>(bufA, xbf, Pl0, Pr0, bl0,
                                             nullptr, h0, h8, N, DIN, DIN);

    // Layer 1: hout fp32 (output 1); hrelu bf16 fragments in-place over h0
    k_agg256_f8<<<aggBlocks, 256, 0, stream>>>(h8, rowptr, colbuf, invd, bufA, N);
    k_gemm_mfma_wide<<<gw, 256, 0, stream>>>(bufA, h0, Pl1, Pr1, bl1,
                                             hout, h0, nullptr, N, DH, DH);

    // Layer 2: U8 = fp8(hrelu@Wl2), out0 = hrelu@Wr2 + bl2; out0 += agg(U8)
    unsigned char* U8 = (unsigned char*)xbf;  // xbf dead after L0 GEMM
    k_gemm_mfma_out<<<(N + 127) / 128, 256, 0, stream>>>(h0, Pl2, Pr2, bl2, U8, out0, N);
    k_agg_add47_f8<<<aggBlocks, 256, 0, stream>>>(U8, rowptr, colbuf, invd, out0, N);
}

// Round 8
// 552.630 us; speedup vs baseline: 1.1628x; 1.0680x over previous
//
#include <hip/hip_runtime.h>
#include <cstdint>
#include <cstddef>

static constexpr int DIN  = 128;
static constexpr int DH   = 256;
static constexpr int DOUT = 47;

typedef __attribute__((ext_vector_type(8))) short bf16x8;
typedef __attribute__((ext_vector_type(4))) float f32x4;
typedef __attribute__((ext_vector_type(2))) float f32x2;

__device__ __forceinline__ short f2bf(float f) {
    unsigned u = __float_as_uint(f);
    unsigned r = (u + 0x7fffu + ((u >> 16) & 1u)) >> 16;  // RNE
    return (short)r;
}

// fp8 e4m3 (HW-native) helpers
__device__ __forceinline__ void addpk(unsigned w, float* a) {
    f32x2 lo = __builtin_amdgcn_cvt_pk_f32_fp8(w, false);
    f32x2 hi = __builtin_amdgcn_cvt_pk_f32_fp8(w, true);
    a[0] += lo[0]; a[1] += lo[1]; a[2] += hi[0]; a[3] += hi[1];
}
__device__ __forceinline__ unsigned enc4(float a, float b, float c, float d) {
    unsigned w = __builtin_amdgcn_cvt_pk_fp8_f32(a, b, 0, false);
    w = __builtin_amdgcn_cvt_pk_fp8_f32(c, d, w, true);
    return w;
}
__device__ __forceinline__ unsigned char enc1(float v) {
    return (unsigned char)(__builtin_amdgcn_cvt_pk_fp8_f32(v, v, 0, false) & 0xff);
}
__device__ __forceinline__ unsigned pbf2(float a, float b, float sc) {
    return (unsigned)(unsigned short)f2bf(a * sc) |
           ((unsigned)(unsigned short)f2bf(b * sc) << 16);
}

// A-fragment layout: value A[row][k] lives at
//   ((tile*nks + ks)*64 + q*16 + r)*8 + j   (shorts)
// with tile=row>>4, r=row&15, ks=k>>5, q=(k>>3)&3, j=k&7.

// ---------------------------------------------------------------------------
// CSR build
__global__ void k_detect(const int* __restrict__ e, int* __restrict__ flag, int nprobe) {
    int i = blockIdx.x * blockDim.x + threadIdx.x;
    if (i < nprobe) {
        if (e[2 * i + 1] != 0) atomicOr(flag, 1);
    }
}

// Legacy fallback path (used only when bucket params don't fit)
__global__ void k_hist(const int* __restrict__ e, const int* __restrict__ flag,
                       int* __restrict__ cnt, int E) {
    int i = blockIdx.x * blockDim.x + threadIdx.x;
    if (i >= E) return;
    int is32 = *flag;
    int d = is32 ? e[E + i] : e[2 * (E + i)];
    atomicAdd(&cnt[d], 1);
}

__global__ void k_fill(const int* __restrict__ e, const int* __restrict__ flag,
                       const int* __restrict__ rowptr, int* __restrict__ cursor,
                       int* __restrict__ colbuf, int E) {
    int i = blockIdx.x * blockDim.x + threadIdx.x;
    if (i >= E) return;
    int is32 = *flag;
    int s = is32 ? e[i] : e[2 * i];
    int d = is32 ? e[E + i] : e[2 * (E + i)];
    int pos = atomicAdd(&cursor[d], 1);
    colbuf[rowptr[d] + pos] = s;
}

__global__ void k_invdeg(const int* __restrict__ rowptr, float* __restrict__ invd, int N) {
    int i = blockIdx.x * blockDim.x + threadIdx.x;
    if (i >= N) return;
    int d = rowptr[i + 1] - rowptr[i];
    invd[i] = 1.0f / (float)(d > 1 ? d : 1);
}

// --- Fast bucketed CSR build ------------------------------------------------
// Per-block int32/int64 layout probe (replaces k_detect in the fast path):
// scans the high words of the first min(E,4096) entries.
__device__ __forceinline__ int block_is32(const int* __restrict__ e, int E, int* sflag) {
    if (threadIdx.x == 0) *sflag = 0;
    __syncthreads();
    int nprobe = E < 4096 ? E : 4096;
    int found = 0;
    for (int i = threadIdx.x; i < nprobe; i += blockDim.x)
        if (e[2 * i + 1] != 0) { found = 1; break; }
    if (found) atomicOr(sflag, 1);
    __syncthreads();
    return *sflag;
}

__launch_bounds__(256)
__global__ void k_binhist(const int* __restrict__ e,
                          int* __restrict__ bucketCnt, int E, int shift, int nbk) {
    __shared__ int h[1024];
    __shared__ int sflag;
    int t = threadIdx.x;
    for (int i = t; i < nbk; i += 256) h[i] = 0;
    int is32 = block_is32(e, E, &sflag);   // includes the needed barriers
    int stride = gridDim.x * 256;
    for (int i = blockIdx.x * 256 + t; i < E; i += stride) {
        int d = is32 ? e[E + i] : e[2 * (E + i)];
        atomicAdd(&h[d >> shift], 1);
    }
    __syncthreads();
    for (int i = t; i < nbk; i += 256) {
        int v = h[i];
        if (v) atomicAdd(&bucketCnt[i], v);
    }
}

__global__ void k_bucket_scan(const int* __restrict__ bucketCnt, int* __restrict__ bucketOff,
                              int* __restrict__ bucketCur, int nbk, int E) {
    __shared__ int s[1024];
    int t = threadIdx.x;
    int v = (t < nbk) ? bucketCnt[t] : 0;
    s[t] = v;
    __syncthreads();
    for (int off = 1; off < 1024; off <<= 1) {
        int xv = (t >= off) ? s[t - off] : 0;
        __syncthreads();
        s[t] += xv;
        __syncthreads();
    }
    if (t < nbk) { bucketOff[t] = s[t] - v; bucketCur[t] = 0; }
    if (t == 0) bucketOff[nbk] = E;
}

__launch_bounds__(256)
__global__ void k_binscatter(const int* __restrict__ e,
                             const int* __restrict__ bucketOff, int* __restrict__ bucketCur,
                             uint2* __restrict__ pairbuf, int E, int shift, int nbk) {
    __shared__ int h[1024];
    __shared__ int cur[1024];
    __shared__ int sflag;
    int t = threadIdx.x;
    for (int i = t; i < nbk; i += 256) h[i] = 0;
    int is32 = block_is32(e, E, &sflag);
    int chunk = (E + gridDim.x - 1) / gridDim.x;
    int lo = blockIdx.x * chunk;
    int hi = lo + chunk < E ? lo + chunk : E;
    for (int i = lo + t; i < hi; i += 256) {
        int d = is32 ? e[E + i] : e[2 * (E + i)];
        atomicAdd(&h[d >> shift], 1);
    }
    __syncthreads();
    for (int i = t; i < nbk; i += 256) {
        int c = h[i];
        int base = c ? atomicAdd(&bucketCur[i], c) : 0;
        h[i] = bucketOff[i] + base;
        cur[i] = 0;
    }
    __syncthreads();
    for (int i = lo + t; i < hi; i += 256) {
        int sv = is32 ? e[i] : e[2 * i];
        int d  = is32 ? e[E + i] : e[2 * (E + i)];
        int b = d >> shift;
        int lp = atomicAdd(&cur[b], 1);
        pairbuf[h[b] + lp] = make_uint2((unsigned)sv, (unsigned)d);
    }
}

// Per-bucket degree histogram -> cnt AND invd (fused k_invdeg).
__launch_bounds__(256)
__global__ void k_bhist(const uint2* __restrict__ pairbuf, const int* __restrict__ bucketOff,
                        int* __restrict__ cnt, float* __restrict__ invd, int shift, int N) {
    __shared__ int h[2048];
    int b = blockIdx.x;
    int t = threadIdx.x;
    int first = b << shift;
    int span = (1 << shift);
    if (first + span > N) span = N - first;
    for (int i = t; i < span; i += 256) h[i] = 0;
    __syncthreads();
    int lo = bucketOff[b], hi = bucketOff[b + 1];
    for (int j = lo + t; j < hi; j += 256) {
        int d = (int)pairbuf[j].y;
        atomicAdd(&h[d - first], 1);
    }
    __syncthreads();
    for (int i = t; i < span; i += 256) {
        int c = h[i];
        cnt[first + i] = c;
        invd[first + i] = 1.0f / (float)(c > 1 ? c : 1);
    }
}

#define FILL_CAP 12288
__launch_bounds__(256)
__global__ void k_fill2(const uint2* __restrict__ pairbuf, const int* __restrict__ bucketOff,
                        const int* __restrict__ rowptr, int* __restrict__ cursor,
                        int* __restrict__ colbuf, int shift, int N) {
    __shared__ int cur[2048];
    __shared__ int sbuf[FILL_CAP];
    int b = blockIdx.x;
    int t = threadIdx.x;
    int first = b << shift;
    int span = (1 << shift);
    if (first + span > N) span = N - first;
    int lo = bucketOff[b], hi = bucketOff[b + 1];
    int nEdge = hi - lo;
    int base = rowptr[first];
    if (nEdge <= FILL_CAP) {
        for (int i = t; i < span; i += 256) cur[i] = rowptr[first + i] - base;
        __syncthreads();
        for (int j = lo + t; j < hi; j += 256) {
            uint2 p = pairbuf[j];
            int lp = atomicAdd(&cur[(int)p.y - first], 1);
            sbuf[lp] = (int)p.x;
        }
        __syncthreads();
        for (int i = t; i < nEdge; i += 256) colbuf[base + i] = sbuf[i];
    } else {
        for (int j = lo + t; j < hi; j += 256) {
            uint2 p = pairbuf[j];
            int d = (int)p.y;
            int pos = atomicAdd(&cursor[d], 1);
            colbuf[rowptr[d] + pos] = (int)p.x;
        }
    }
}

__global__ void k_chunk_sum(const int* __restrict__ cnt, int* __restrict__ csum, int n) {
    int base = blockIdx.x * 1024;
    int t = threadIdx.x;
    int s = 0;
#pragma unroll
    for (int j = 0; j < 4; j++) {
        int i = base + t * 4 + j;
        if (i < n) s += cnt[i];
    }
    __shared__ int red[256];
    red[t] = s;
    __syncthreads();
    for (int off = 128; off > 0; off >>= 1) {
        if (t < off) red[t] += red[t + off];
        __syncthreads();
    }
    if (t == 0) csum[blockIdx.x] = red[0];
}

__global__ void k_scan_csum(int* __restrict__ csum, int n,
                            int* __restrict__ rowptr, int N, int E) {
    __shared__ int s[128];
    int t = threadIdx.x;
    int v = (t < n) ? csum[t] : 0;
    s[t] = v;
    __syncthreads();
    for (int off = 1; off < 128; off <<= 1) {
        int xv = (t >= off) ? s[t - off] : 0;
        __syncthreads();
        s[t] += xv;
        __syncthreads();
    }
    if (t < n) csum[t] = s[t] - v;  // exclusive
    if (t == 0) rowptr[N] = E;
}

__global__ void k_scan_apply(const int* __restrict__ cnt, const int* __restrict__ csum,
                             int* __restrict__ rowptr, int n) {
    int base = blockIdx.x * 1024, t = threadIdx.x;
    int i0 = base + t * 4;
    int v[4];
#pragma unroll
    for (int j = 0; j < 4; j++) {
        int i = i0 + j;
        v[j] = (i < n) ? cnt[i] : 0;
    }
    int tsum = v[0] + v[1] + v[2] + v[3];
    __shared__ int s[256];
    s[t] = tsum;
    __syncthreads();
    for (int off = 1; off < 256; off <<= 1) {
        int xv = (t >= off) ? s[t - off] : 0;
        __syncthreads();
        s[t] += xv;
        __syncthreads();
    }
    int excl = s[t] - tsum + csum[blockIdx.x];
#pragma unroll
    for (int j = 0; j < 4; j++) {
        int i = i0 + j;
        if (i < n) rowptr[i] = excl;
        excl += v[j];
    }
}

// ---------------------------------------------------------------------------
// fp32 x -> bf16 A-fragments (GEMM A2, nks=4) + fp8 row-major (gather table).
__global__ void k_f2bf8(const float* __restrict__ X, short* __restrict__ Yb,
                        unsigned* __restrict__ Y8, int nTiles, int N) {
    int t = blockIdx.x * 256 + threadIdx.x;
    int total = nTiles * 4 * 64;
    if (t >= total) return;
    int lane = t & 63;
    int kt = t >> 6;          // tile*4 + ks
    int ks = kt & 3;
    int tile = kt >> 2;
    int q = (lane >> 4) & 3;
    int r = lane & 15;
    int row = tile * 16 + r;
    int col = ks * 32 + q * 8;
    bf16x8 o = (bf16x8)(short)0;
    if (row < N) {
        const float* src = X + (size_t)row * DIN + col;
        float4 v0 = *(const float4*)src;
        float4 v1 = *(const float4*)(src + 4);
        o[0] = f2bf(v0.x); o[1] = f2bf(v0.y); o[2] = f2bf(v0.z); o[3] = f2bf(v0.w);
        o[4] = f2bf(v1.x); o[5] = f2bf(v1.y); o[6] = f2bf(v1.z); o[7] = f2bf(v1.w);
        unsigned* p8 = Y8 + ((size_t)row * DIN + col) / 4;
        p8[0] = enc4(v0.x, v0.y, v0.z, v0.w);
        p8[1] = enc4(v1.x, v1.y, v1.z, v1.w);
    }
    *(bf16x8*)(Yb + (size_t)t * 8) = o;
}

// All six weight packs in ONE launch. Tile map (64-thread tiles):
// [0,64) Wl0 | [64,128) Wr0 | [128,256) Wl1 | [256,384) Wr1 | [384,408) Wl2 | [408,432) Wr2
__global__ void k_pack_all(const float* __restrict__ Wl0, short* __restrict__ Pl0,
                           const float* __restrict__ Wr0, short* __restrict__ Pr0,
                           const float* __restrict__ Wl1, short* __restrict__ Pl1,
                           const float* __restrict__ Wr1, short* __restrict__ Pr1,
                           const float* __restrict__ Wl2, short* __restrict__ Pl2,
                           const float* __restrict__ Wr2, short* __restrict__ Pr2) {
    int idx = blockIdx.x * 256 + threadIdx.x;
    if (idx >= 432 * 64) return;
    int lane = idx & 63;
    int t = idx >> 6;
    const float* W; short* P; int Nt, Ncols, tl;
    if (t < 64)       { W = Wl0; P = Pl0; Nt = 16; Ncols = 256;  tl = t; }
    else if (t < 128) { W = Wr0; P = Pr0; Nt = 16; Ncols = 256;  tl = t - 64; }
    else if (t < 256) { W = Wl1; P = Pl1; Nt = 16; Ncols = 256;  tl = t - 128; }
    else if (t < 384) { W = Wr1; P = Pr1; Nt = 16; Ncols = 256;  tl = t - 256; }
    else if (t < 408) { W = Wl2; P = Pl2; Nt = 3;  Ncols = DOUT; tl = t - 384; }
    else              { W = Wr2; P = Pr2; Nt = 3;  Ncols = DOUT; tl = t - 408; }
    int nt = tl % Nt;
    int ks = tl / Nt;
    int n = nt * 16 + (lane & 15);
    int kb = ks * 32 + (lane >> 4) * 8;
    bf16x8 o;
#pragma unroll
    for (int j = 0; j < 8; j++)
        o[j] = (n < Ncols) ? f2bf(W[(size_t)(kb + j) * Ncols + n]) : (short)0;
    *(bf16x8*)(P + (size_t)tl * 64 * 8 + lane * 8) = o;
}

// ---------------------------------------------------------------------------
// 256-wide fp8 CSR mean-agg. Output: bf16 A-fragments (nks=8).
__launch_bounds__(256)
__global__ void k_agg256_f8(const unsigned char* __restrict__ X8, const int* __restrict__ rowptr,
                            const int* __restrict__ colv, const float* __restrict__ invd,
                            short* __restrict__ out, int N) {
    const int lane = threadIdx.x & 63;
    const int node = blockIdx.x * 4 + (threadIdx.x >> 6);
    if (node >= N) return;
    int beg = __builtin_amdgcn_readfirstlane(rowptr[node]);
    int end = __builtin_amdgcn_readfirstlane(rowptr[node + 1]);
    const int q = lane >> 4, sub = lane & 15;
    const unsigned char* Xs = X8 + sub * 16;

    float acc[16];
#pragma unroll
    for (int c = 0; c < 16; c++) acc[c] = 0.f;

    auto addv = [&](uint4 a) {
        addpk(a.x, acc); addpk(a.y, acc + 4); addpk(a.z, acc + 8); addpk(a.w, acc + 12);
    };

    int j = beg;
    for (; j + 7 < end; j += 8) {
        int i0 = colv[j], i1 = colv[j + 1], i2 = colv[j + 2], i3 = colv[j + 3];
        int i4 = colv[j + 4], i5 = colv[j + 5], i6 = colv[j + 6], i7 = colv[j + 7];
        int sA = (q == 0) ? i0 : (q == 1) ? i1 : (q == 2) ? i2 : i3;
        int sB = (q == 0) ? i4 : (q == 1) ? i5 : (q == 2) ? i6 : i7;
        uint4 a = *(const uint4*)(Xs + (size_t)sA * 256);
        uint4 b = *(const uint4*)(Xs + (size_t)sB * 256);
        addv(a); addv(b);
    }
    if (j + 3 < end) {
        int i0 = colv[j], i1 = colv[j + 1], i2 = colv[j + 2], i3 = colv[j + 3];
        int sA = (q == 0) ? i0 : (q == 1) ? i1 : (q == 2) ? i2 : i3;
        uint4 a = *(const uint4*)(Xs + (size_t)sA * 256);
        addv(a);
        j += 4;
    }
    int rem = end - j;
    if (rem > 0) {
        int i0 = colv[j];
        int i1 = rem > 1 ? colv[j + 1] : i0;
        int i2 = rem > 2 ? colv[j + 2] : i0;
        int s = (q == 1) ? i1 : (q == 2) ? i2 : i0;
        uint4 a = *(const uint4*)(Xs + (size_t)s * 256);
        if (q < rem) addv(a);
    }

#pragma unroll
    for (int c = 0; c < 16; c++) {
        acc[c] += __shfl_xor(acc[c], 16);
        acc[c] += __shfl_xor(acc[c], 32);
    }

    if (q == 0) {
        float sc = invd[node];
        uint4 o0, o1;
        o0.x = pbf2(acc[0], acc[1], sc);   o0.y = pbf2(acc[2], acc[3], sc);
        o0.z = pbf2(acc[4], acc[5], sc);   o0.w = pbf2(acc[6], acc[7], sc);
        o1.x = pbf2(acc[8], acc[9], sc);   o1.y = pbf2(acc[10], acc[11], sc);
        o1.z = pbf2(acc[12], acc[13], sc); o1.w = pbf2(acc[14], acc[15], sc);
        const int tile = node >> 4, r = node & 15;
        const int ksC = sub >> 1, q1 = (sub & 1) * 2;
        size_t base = ((size_t)(tile * 8 + ksC) * 64 + r) * 8;
        *(uint4*)(out + base + (size_t)q1 * 128)       = o0;
        *(uint4*)(out + base + (size_t)(q1 + 1) * 128) = o1;
    }
}

// 128-wide fp8 CSR mean-agg. Output: bf16 A-fragments (nks=4).
__launch_bounds__(256)
__global__ void k_agg128_f8(const unsigned char* __restrict__ X8, const int* __restrict__ rowptr,
                            const int* __restrict__ colv, const float* __restrict__ invd,
                            short* __restrict__ out, int N) {
    const int lane = threadIdx.x & 63;
    const int node = blockIdx.x * 4 + (threadIdx.x >> 6);
    if (node >= N) return;
    int beg = __builtin_amdgcn_readfirstlane(rowptr[node]);
    int end = __builtin_amdgcn_readfirstlane(rowptr[node + 1]);
    const int grp = lane >> 3, sub = lane & 7;
    const unsigned char* Xs = X8 + sub * 16;

    float acc[16];
#pragma unroll
    for (int c = 0; c < 16; c++) acc[c] = 0.f;

    auto addv = [&](uint4 a) {
        addpk(a.x, acc); addpk(a.y, acc + 4); addpk(a.z, acc + 8); addpk(a.w, acc + 12);
    };

    int j = beg;
    for (; j + 15 < end; j += 16) {
        int sA = colv[j + grp];
        int sB = colv[j + 8 + grp];
        uint4 a = *(const uint4*)(Xs + (size_t)sA * 128);
        uint4 b = *(const uint4*)(Xs + (size_t)sB * 128);
        addv(a); addv(b);
    }
    if (j + 7 < end) {
        int sA = colv[j + grp];
        uint4 a = *(const uint4*)(Xs + (size_t)sA * 128);
        addv(a);
        j += 8;
    }
    int rem = end - j;
    if (rem > 0) {
        int sA = colv[j + (grp < rem ? grp : 0)];
        uint4 a = *(const uint4*)(Xs + (size_t)sA * 128);
        if (grp < rem) addv(a);
    }

#pragma unroll
    for (int c = 0; c < 16; c++) {
        acc[c] += __shfl_xor(acc[c], 8);
        acc[c] += __shfl_xor(acc[c], 16);
        acc[c] += __shfl_xor(acc[c], 32);
    }

    if (grp == 0) {
        float sc = invd[node];
        uint4 o0, o1;
        o0.x = pbf2(acc[0], acc[1], sc);   o0.y = pbf2(acc[2], acc[3], sc);
        o0.z = pbf2(acc[4], acc[5], sc);   o0.w = pbf2(acc[6], acc[7], sc);
        o1.x = pbf2(acc[8], acc[9], sc);   o1.y = pbf2(acc[10], acc[11], sc);
        o1.z = pbf2(acc[12], acc[13], sc); o1.w = pbf2(acc[14], acc[15], sc);
        const int tile = node >> 4, r = node & 15;
        const int ksC = sub >> 1, q1 = (sub & 1) * 2;
        size_t base = ((size_t)(tile * 4 + ksC) * 64 + r) * 8;
        *(uint4*)(out + base + (size_t)q1 * 128)       = o0;
        *(uint4*)(out + base + (size_t)(q1 + 1) * 128) = o1;
    }
}

// ---------------------------------------------------------------------------
// LDS-free dual-A bf16 MFMA GEMM; A in fragment order, dist-1 prefetch,
// acc[2][4], 32-row blocks. Cb (fragment order, nks=8) and C8 (row-major)
// staged in LDS, written as dense full-line copies.
__launch_bounds__(256, 4)
__global__ void k_gemm_mfma_wide(const short* __restrict__ A1, const short* A2,
                                 const short* __restrict__ P1, const short* __restrict__ P2,
                                 const float* __restrict__ bias,
                                 float* Cf, short* Cb, unsigned char* C8,
                                 int M, int K1, int K2) {
    __shared__ short sCb[8192];            // 2 tiles x 8 ks x 64 lanes x 8 shorts
    __shared__ unsigned char sC8[8192];    // 32 rows x 256 cols
    const int lane = threadIdx.x & 63;
    const int wave = threadIdx.x >> 6;
    const int quad = lane >> 4;
    const int r    = lane & 15;
    const int rowBase = blockIdx.x * 32;
    const int tile0 = blockIdx.x * 2;

    f32x4 acc[2][4];
#pragma unroll
    for (int mt = 0; mt < 2; mt++)
#pragma unroll
        for (int nt = 0; nt < 4; nt++) acc[mt][nt] = (f32x4)(0.f);

    for (int src = 0; src < 2; src++) {
        const short* A = src ? A2 : A1;
        const short* P = src ? P2 : P1;
        const int K = src ? K2 : K1;
        const int nks = K >> 5;

        bf16x8 af[2], bfr[4];
#pragma unroll
        for (int mt = 0; mt < 2; mt++)
            af[mt] = *(const bf16x8*)(A + (((size_t)(tile0 + mt) * nks * 64 + lane) << 3));
#pragma unroll
        for (int nt = 0; nt < 4; nt++)
            bfr[nt] = *(const bf16x8*)(P + (((size_t)(wave * 4 + nt) * 64 + lane) << 3));

        for (int ks = 0; ks < nks; ks++) {
            const int ksn = (ks + 1 < nks) ? ks + 1 : ks;
            bf16x8 afn[2], bfn[4];
#pragma unroll
            for (int mt = 0; mt < 2; mt++)
                afn[mt] = *(const bf16x8*)(A + ((((size_t)(tile0 + mt) * nks + ksn) * 64 + lane) << 3));
#pragma unroll
            for (int nt = 0; nt < 4; nt++)
                bfn[nt] = *(const bf16x8*)(P + (((size_t)(ksn * 16 + wave * 4 + nt) * 64 + lane) << 3));
#pragma unroll
            for (int mt = 0; mt < 2; mt++)
#pragma unroll
                for (int nt = 0; nt < 4; nt++)
                    acc[mt][nt] = __builtin_amdgcn_mfma_f32_16x16x32_bf16(
                        af[mt], bfr[nt], acc[mt][nt], 0, 0, 0);
#pragma unroll
            for (int mt = 0; mt < 2; mt++) af[mt] = afn[mt];
#pragma unroll
            for (int nt = 0; nt < 4; nt++) bfr[nt] = bfn[nt];
        }
    }

    __syncthreads();  // guard in-place Cb == A2 (block touches only its own tiles)

    float bv[4];
#pragma unroll
    for (int nt = 0; nt < 4; nt++) bv[nt] = bias[wave * 64 + nt * 16 + r];

#pragma unroll
    for (int mt = 0; mt < 2; mt++) {
#pragma unroll
        for (int reg = 0; reg < 4; reg++) {
            int rC = quad * 4 + reg;
            int row = rowBase + mt * 16 + rC;
#pragma unroll
            for (int nt = 0; nt < 4; nt++) {
                int col = wave * 64 + nt * 16 + r;
                float v = acc[mt][nt][reg] + bv[nt];
                if (Cf && row < M) Cf[(size_t)row * 256 + col] = v;
                if (Cb) {
                    int ksC = wave * 2 + (nt >> 1);
                    int qC  = (nt & 1) * 2 + (r >> 3);
                    sCb[(((mt * 8 + ksC) * 64 + qC * 16 + rC) << 3) + (r & 7)] = f2bf(fmaxf(v, 0.f));
                }
                if (C8) sC8[(mt * 16 + rC) * 256 + col] = enc1(fmaxf(v, 0.f));
            }
        }
    }

    __syncthreads();
    if (Cb) {
        uint4* d = (uint4*)(Cb + ((size_t)tile0 << 12));
        const uint4* s = (const uint4*)sCb;
        for (int i = threadIdx.x; i < 1024; i += 256) d[i] = s[i];
    }
    if (C8) {
        uint4* d = (uint4*)(C8 + ((size_t)rowBase << 8));
        const uint4* s = (const uint4*)sC8;
        for (int i = threadIdx.x; i < 512; i += 256) d[i] = s[i];
    }
}

// Layer-2 fused dual-W MFMA: U (fp8, stride 48, LDS-staged dense write) +
// Out (fp32, [M,47], direct). A in fragment order (nks=8), dist-1 prefetch.
__launch_bounds__(256, 4)
__global__ void k_gemm_mfma_out(const short* __restrict__ A,
                                const short* __restrict__ Pl, const short* __restrict__ Pr,
                                const float* __restrict__ bias,
                                unsigned char* __restrict__ U8, float* __restrict__ Out, int M) {
    __shared__ unsigned char sU8[6144];    // 128 rows x 48B
    const int lane = threadIdx.x & 63;
    const int wave = threadIdx.x >> 6;
    const int quad = lane >> 4;
    const int r    = lane & 15;
    const int tile0 = blockIdx.x * 8 + wave * 2;

    f32x4 aU[2][3], aO[2][3];
#pragma unroll
    for (int mt = 0; mt < 2; mt++)
#pragma unroll
        for (int nt = 0; nt < 3; nt++) { aU[mt][nt] = (f32x4)(0.f); aO[mt][nt] = (f32x4)(0.f); }

    bf16x8 af[2];
#pragma unroll
    for (int mt = 0; mt < 2; mt++)
        af[mt] = *(const bf16x8*)(A + (((size_t)(tile0 + mt) * 8 * 64 + lane) << 3));

    for (int ks = 0; ks < 8; ks++) {
        const int ksn = (ks + 1 < 8) ? ks + 1 : ks;
        bf16x8 afn[2], bl[3], br[3];
#pragma unroll
        for (int mt = 0; mt < 2; mt++)
            afn[mt] = *(const bf16x8*)(A + ((((size_t)(tile0 + mt) * 8 + ksn) * 64 + lane) << 3));
#pragma unroll
        for (int nt = 0; nt < 3; nt++) {
            size_t fo = (((size_t)(ks * 3 + nt) * 64 + lane) << 3);
            bl[nt] = *(const bf16x8*)(Pl + fo);
            br[nt] = *(const bf16x8*)(Pr + fo);
        }
#pragma unroll
        for (int mt = 0; mt < 2; mt++)
#pragma unroll
            for (int nt = 0; nt < 3; nt++) {
                aU[mt][nt] = __builtin_amdgcn_mfma_f32_16x16x32_bf16(af[mt], bl[nt], aU[mt][nt], 0, 0, 0);
                aO[mt][nt] = __builtin_amdgcn_mfma_f32_16x16x32_bf16(af[mt], br[nt], aO[mt][nt], 0, 0, 0);
            }
#pragma unroll
        for (int mt = 0; mt < 2; mt++) af[mt] = afn[mt];
    }

    float bv[3];
#pragma unroll
    for (int nt = 0; nt < 3; nt++) {
        int col = nt * 16 + r;
        bv[nt] = (col < DOUT) ? bias[col] : 0.f;
    }

#pragma unroll
    for (int mt = 0; mt < 2; mt++) {
#pragma unroll
        for (int reg = 0; reg < 4; reg++) {
            int rloc = wave * 32 + mt * 16 + quad * 4 + reg;
            int row = blockIdx.x * 128 + rloc;
#pragma unroll
            for (int nt = 0; nt < 3; nt++) {
                int col = nt * 16 + r;
                sU8[rloc * 48 + col] = enc1(aU[mt][nt][reg]);
                if (row < M && col < DOUT) Out[(size_t)row * DOUT + col] = aO[mt][nt][reg] + bv[nt];
            }
        }
    }

    __syncthreads();
    {
        uint4* d = (uint4*)(U8 + (size_t)blockIdx.x * 6144);
        const uint4* s = (const uint4*)sU8;
        for (int i = threadIdx.x; i < 384; i += 256) d[i] = s[i];
    }
}

// out0[dst,:] += inv_deg[dst] * mean-agg of U8 rows (fp8, stride 48).
__launch_bounds__(256)
__global__ void k_agg_add47_f8(const unsigned char* __restrict__ U8, const int* __restrict__ rowptr,
                               const int* __restrict__ colv, const float* __restrict__ invd,
                               float* __restrict__ out0, int N) {
    const int lane = threadIdx.x & 63;
    const int node = blockIdx.x * 4 + (threadIdx.x >> 6);
    if (node >= N) return;
    int beg = __builtin_amdgcn_readfirstlane(rowptr[node]);
    int end = __builtin_amdgcn_readfirstlane(rowptr[node + 1]);
    const int q = lane >> 4, sub = lane & 15;
    const bool act = sub < 12;
    const unsigned char* Us = U8 + sub * 4;

    float acc[4] = {0.f, 0.f, 0.f, 0.f};

    int j = beg;
    for (; j + 7 < end; j += 8) {
        int i0 = colv[j], i1 = colv[j + 1], i2 = colv[j + 2], i3 = colv[j + 3];
        int i4 = colv[j + 4], i5 = colv[j + 5], i6 = colv[j + 6], i7 = colv[j + 7];
        int sA = (q == 0) ? i0 : (q == 1) ? i1 : (q == 2) ? i2 : i3;
        int sB = (q == 0) ? i4 : (q == 1) ? i5 : (q == 2) ? i6 : i7;
        if (act) {
            unsigned a = *(const unsigned*)(Us + (size_t)sA * 48);
            unsigned b = *(const unsigned*)(Us + (size_t)sB * 48);
            addpk(a, acc); addpk(b, acc);
        }
    }
    if (j + 3 < end) {
        int i0 = colv[j], i1 = colv[j + 1], i2 = colv[j + 2], i3 = colv[j + 3];
        int sA = (q == 0) ? i0 : (q == 1) ? i1 : (q == 2) ? i2 : i3;
        if (act) {
            unsigned a = *(const unsigned*)(Us + (size_t)sA * 48);
            addpk(a, acc);
        }
        j += 4;
    }
    int rem = end - j;
    if (rem > 0) {
        int i0 = colv[j];
        int i1 = rem > 1 ? colv[j + 1] : i0;
        int i2 = rem > 2 ? colv[j + 2] : i0;
        int s = (q == 1) ? i1 : (q == 2) ? i2 : i0;
        if (act && q < rem) {
            unsigned a = *(const unsigned*)(Us + (size_t)s * 48);
            addpk(a, acc);
        }
    }

#pragma unroll
    for (int c = 0; c < 4; c++) {
        acc[c] += __shfl_xor(acc[c], 16);
        acc[c] += __shfl_xor(acc[c], 32);
    }

    if (q == 0 && act) {
        float sc = invd[node];
        int f0 = sub * 4;
        float* op = out0 + (size_t)node * DOUT;
#pragma unroll
        for (int c = 0; c < 4; c++)
            if (f0 + c < DOUT) op[f0 + c] += sc * acc[c];
    }
}

// ---------------------------------------------------------------------------
extern "C" void kernel_launch(void* const* d_in, const int* in_sizes, int n_in,
                              void* d_out, int out_size, void* d_ws, size_t ws_size,
                              hipStream_t stream) {
    const float* x   = (const float*)d_in[0];
    const int*   ei  = (const int*)d_in[1];
    const float* Wl0 = (const float*)d_in[2];
    const float* bl0 = (const float*)d_in[3];
    const float* Wr0 = (const float*)d_in[4];
    const float* Wl1 = (const float*)d_in[5];
    const float* bl1 = (const float*)d_in[6];
    const float* Wr1 = (const float*)d_in[7];
    const float* Wl2 = (const float*)d_in[8];
    const float* bl2 = (const float*)d_in[9];
    const float* Wr2 = (const float*)d_in[10];

    const int N = in_sizes[0] / DIN;
    const int E = in_sizes[1] / 2;
    const int nTiles = (N + 15) / 16;
    const size_t Mpad = (size_t)nTiles * 16 + 128;   // padded rows for fragment buffers

    char* p = (char*)d_ws;
    auto alloc = [&](size_t bytes) -> char* {
        char* r = p;
        p += (bytes + 255) & ~(size_t)255;
        return r;
    };
    int*   flag   = (int*)alloc(4);
    int*   cnt    = (int*)alloc((size_t)N * 4);
    int*   rowptr = (int*)alloc((size_t)(N + 1) * 4);
    int*   csum   = (int*)alloc(1024 * 4);
    int*   colbuf = (int*)alloc((size_t)E * 4 + 64);
    float* invd   = (float*)alloc((size_t)N * 4);
    int*   bucketCnt = (int*)alloc(1025 * 4);
    int*   bucketOff = (int*)alloc(1025 * 4);
    int*   bucketCur = (int*)alloc(1024 * 4);
    short* xbf    = (short*)alloc(Mpad * DIN * 2);   // x bf16 fragments; later reused as U8 [*,48] fp8
    short* bufA   = (short*)alloc(Mpad * DH * 2);    // agg output fragments; pre-agg: pairbuf
    short* h0     = (short*)alloc(Mpad * DH * 2);    // h0 bf16 fragments; hrelu in-place after L1
    unsigned*      x8 = (unsigned*)alloc((size_t)N * DIN);  // fp8 x (gather table, row-major)
    unsigned char* h8 = (unsigned char*)alloc(Mpad * DH);   // fp8 relu(h0) (gather table, padded)
    short* Pl0    = (short*)alloc((size_t)DIN * 256 * 2);
    short* Pr0    = (short*)alloc((size_t)DIN * 256 * 2);
    short* Pl1    = (short*)alloc((size_t)DH * 256 * 2);
    short* Pr1    = (short*)alloc((size_t)DH * 256 * 2);
    short* Pl2    = (short*)alloc((size_t)DH * 48 * 2);
    short* Pr2    = (short*)alloc((size_t)DH * 48 * 2);

    float* out0 = (float*)d_out;                        // [N,47]
    float* hout = (float*)d_out + (size_t)N * DOUT;     // [N,256] fp32 (output 1)

    // Bucketed CSR parameters: smallest span >= 128 with <= 1024 buckets.
    int span_shift = 7;
    while ((((N - 1) >> span_shift) + 1) > 1024 && span_shift < 21) span_shift++;
    const int NBK = ((N - 1) >> span_shift) + 1;
    const bool fast_csr = (NBK <= 1024) && ((1 << span_shift) <= 2048) &&
                          ((size_t)E * 8 <= Mpad * DH * 2);
    uint2* pairbuf = (uint2*)bufA;  // bufA dead until L0 agg

    // --- CSR build ---
    if (fast_csr) {
        hipMemsetAsync(bucketCnt, 0, (size_t)NBK * 4, stream);
        k_binhist<<<256, 256, 0, stream>>>(ei, bucketCnt, E, span_shift, NBK);
        k_bucket_scan<<<1, 1024, 0, stream>>>(bucketCnt, bucketOff, bucketCur, NBK, E);
        k_binscatter<<<256, 256, 0, stream>>>(ei, bucketOff, bucketCur, pairbuf, E, span_shift, NBK);
        k_bhist<<<NBK, 256, 0, stream>>>(pairbuf, bucketOff, cnt, invd, span_shift, N);
    } else {
        hipMemsetAsync(flag, 0, 4, stream);
        hipMemsetAsync(cnt, 0, (size_t)N * 4, stream);
        const int nprobe = E < 4096 ? E : 4096;
        k_detect<<<(nprobe + 255) / 256, 256, 0, stream>>>(ei, flag, nprobe);
        k_hist<<<(E + 255) / 256, 256, 0, stream>>>(ei, flag, cnt, E);
    }
    const int nchunks = (N + 1023) / 1024;
    k_chunk_sum<<<nchunks, 256, 0, stream>>>(cnt, csum, N);
    k_scan_csum<<<1, 128, 0, stream>>>(csum, nchunks, rowptr, N, E);
    k_scan_apply<<<nchunks, 256, 0, stream>>>(cnt, csum, rowptr, N);
    hipMemsetAsync(cnt, 0, (size_t)N * 4, stream);   // cursor for fill fallback branch
    if (fast_csr) {
        k_fill2<<<NBK, 256, 0, stream>>>(pairbuf, bucketOff, rowptr, cnt, colbuf, span_shift, N);
    } else {
        k_fill<<<(E + 255) / 256, 256, 0, stream>>>(ei, flag, rowptr, cnt, colbuf, E);
        k_invdeg<<<(N + 255) / 256, 256, 0, stream>>>(rowptr, invd, N);
    }

    // --- weight packing + x conversion ---
    k_pack_all<<<(432 * 64 + 255) / 256, 256, 0, stream>>>(Wl0, Pl0, Wr0, Pr0,
                                                           Wl1, Pl1, Wr1, Pr1,
                                                           Wl2, Pl2, Wr2, Pr2);
    k_f2bf8<<<nTiles, 256, 0, stream>>>(x, xbf, x8, nTiles, N);

    const int aggBlocks = (N + 3) / 4;
    const int gw = (N + 31) / 32;

    // Layer 0: h0 = bf16(relu(...)) fragments, h8 = fp8(relu(...)) row-major
    k_agg128_f8<<<aggBlocks, 256, 0, stream>>>((const unsigned char*)x8, rowptr, colbuf, invd, bufA, N);
    k_gemm_mfma_wide<<<gw, 256, 0, stream>>>(bufA, xbf, Pl0, Pr0, bl0,
                                             nullptr, h0, h8, N, DIN, DIN);

    // Layer 1: hout fp32 (output 1); hrelu bf16 fragments in-place over h0
    k_agg256_f8<<<aggBlocks, 256, 0, stream>>>(h8, rowptr, colbuf, invd, bufA, N);
    k_gemm_mfma_wide<<<gw, 256, 0, stream>>>(bufA, h0, Pl1, Pr1, bl1,
                                             hout, h0, nullptr, N, DH, DH);

    // Layer 2: U8 = fp8(hrelu@Wl2), out0 = hrelu@Wr2 + bl2; out0 += agg(U8)
    unsigned char* U8 = (unsigned char*)xbf;  // xbf dead after L0 GEMM
    k_gemm_mfma_out<<<(N + 127) / 128, 256, 0, stream>>>(h0, Pl2, Pr2, bl2, U8, out0, N);
    k_agg_add47_f8<<<aggBlocks, 256, 0, stream>>>(U8, rowptr, colbuf, invd, out0, N);
}